// Round 1
// baseline (1669.035 us; speedup 1.0000x reference)
//
#include <hip/hip_runtime.h>

#define NREL   50
#define NBASE  30
#define HID    16
#define NCLS   8

// ---------------- kernels ----------------

__global__ void init_h_kernel(const float* __restrict__ root1,
                              const float* __restrict__ bias1,
                              float* __restrict__ h, int NH) {
    int i = blockIdx.x * blockDim.x + threadIdx.x;
    if (i < NH) h[i] = root1[i] + bias1[i & (HID - 1)];
}

__global__ void compute_w2_kernel(const float* __restrict__ comp2,
                                  const float* __restrict__ basis2,
                                  float* __restrict__ w2) {
    int i = blockIdx.x * blockDim.x + threadIdx.x;   // r*H*C + h*C + c
    if (i >= NREL * HID * NCLS) return;
    int r  = i / (HID * NCLS);
    int hc = i % (HID * NCLS);
    float acc = 0.f;
    #pragma unroll
    for (int b = 0; b < NBASE; ++b)
        acc += comp2[r * NBASE + b] * basis2[b * HID * NCLS + hc];
    w2[i] = acc;
}

__global__ void count_kernel(const int* __restrict__ dst,
                             const int* __restrict__ et,
                             float* __restrict__ cnt, int E) {
    int e = blockIdx.x * blockDim.x + threadIdx.x;
    if (e < E) atomicAdd(&cnt[dst[e] * NREL + et[e]], 1.0f);
}

// layer 1: 16 threads per edge, one per hidden channel.
// msg[e,h] = inv_e * sum_b comp1[rel,b] * basis1[b, src, h]  -> atomicAdd h[dst,h]
__global__ void layer1_kernel(const int* __restrict__ src,
                              const int* __restrict__ dst,
                              const int* __restrict__ et,
                              const float* __restrict__ comp1,
                              const float* __restrict__ basis1,
                              const float* __restrict__ cnt,
                              float* __restrict__ h, int E, int N) {
    int idx = blockIdx.x * blockDim.x + threadIdx.x;
    int e = idx >> 4;
    if (e >= E) return;
    int hh = idx & 15;
    int s = src[e];
    int d = dst[e];
    int t = et[e];
    float inv = 1.0f / cnt[d * NREL + t];
    const float* c1 = comp1 + t * NBASE;
    long base   = (long)s * HID + hh;
    long stride = (long)N * HID;
    float acc = 0.f;
    #pragma unroll
    for (int b = 0; b < NBASE; ++b)
        acc += c1[b] * basis1[base + (long)b * stride];
    atomicAdd(&h[d * HID + hh], inv * acc);
}

// out init: out[n,c] = bias2[c] + sum_h h[n,h] * root2[h,c]
__global__ void out_init_kernel(const float* __restrict__ h,
                                const float* __restrict__ root2,
                                const float* __restrict__ bias2,
                                float* __restrict__ out, int N) {
    int n = blockIdx.x * blockDim.x + threadIdx.x;
    if (n >= N) return;
    float hr[HID];
    const float4* h4 = reinterpret_cast<const float4*>(h + (size_t)n * HID);
    #pragma unroll
    for (int i = 0; i < HID / 4; ++i) {
        float4 v = h4[i];
        hr[4 * i + 0] = v.x; hr[4 * i + 1] = v.y;
        hr[4 * i + 2] = v.z; hr[4 * i + 3] = v.w;
    }
    float acc[NCLS];
    #pragma unroll
    for (int c = 0; c < NCLS; ++c) acc[c] = bias2[c];
    #pragma unroll
    for (int i = 0; i < HID; ++i) {
        float hv = hr[i];
        #pragma unroll
        for (int c = 0; c < NCLS; ++c)
            acc[c] += hv * root2[i * NCLS + c];
    }
    #pragma unroll
    for (int c = 0; c < NCLS; ++c) out[(size_t)n * NCLS + c] = acc[c];
}

// layer 2: one thread per edge.
// out[d,c] += inv_e * sum_h h[s,h] * w2[rel,h,c]
__global__ void layer2_kernel(const int* __restrict__ src,
                              const int* __restrict__ dst,
                              const int* __restrict__ et,
                              const float* __restrict__ w2,
                              const float* __restrict__ cnt,
                              const float* __restrict__ h,
                              float* __restrict__ out, int E) {
    int e = blockIdx.x * blockDim.x + threadIdx.x;
    if (e >= E) return;
    int s = src[e];
    int d = dst[e];
    int t = et[e];
    float inv = 1.0f / cnt[d * NREL + t];
    const float* w = w2 + t * HID * NCLS;

    float hr[HID];
    const float4* h4 = reinterpret_cast<const float4*>(h + (size_t)s * HID);
    #pragma unroll
    for (int i = 0; i < HID / 4; ++i) {
        float4 v = h4[i];
        hr[4 * i + 0] = v.x; hr[4 * i + 1] = v.y;
        hr[4 * i + 2] = v.z; hr[4 * i + 3] = v.w;
    }
    float acc[NCLS] = {0.f, 0.f, 0.f, 0.f, 0.f, 0.f, 0.f, 0.f};
    #pragma unroll
    for (int i = 0; i < HID; ++i) {
        float hv = hr[i];
        #pragma unroll
        for (int c = 0; c < NCLS; ++c)
            acc[c] += hv * w[i * NCLS + c];
    }
    #pragma unroll
    for (int c = 0; c < NCLS; ++c)
        atomicAdd(&out[(size_t)d * NCLS + c], inv * acc[c]);
}

// ---------------- launch ----------------

extern "C" void kernel_launch(void* const* d_in, const int* in_sizes, int n_in,
                              void* d_out, int out_size, void* d_ws, size_t ws_size,
                              hipStream_t stream) {
    const int*   edge_index = (const int*)  d_in[0];   // [2,E]
    const int*   edge_type  = (const int*)  d_in[1];   // [E]
    const float* basis1     = (const float*)d_in[2];   // [B,N,H]
    const float* comp1      = (const float*)d_in[3];   // [R,B]
    const float* root1      = (const float*)d_in[4];   // [N,H]
    const float* bias1      = (const float*)d_in[5];   // [H]
    const float* basis2     = (const float*)d_in[6];   // [B,H,C]
    const float* comp2      = (const float*)d_in[7];   // [R,B]
    const float* root2      = (const float*)d_in[8];   // [H,C]
    const float* bias2      = (const float*)d_in[9];   // [C]
    float* out = (float*)d_out;

    const int E = in_sizes[1];
    const int N = in_sizes[4] / HID;
    const int* src = edge_index;
    const int* dst = edge_index + E;

    // workspace layout (floats): cnt[N*R] | h[N*H] | w2[R*H*C]
    float* ws  = (float*)d_ws;
    float* cnt = ws;
    float* h   = cnt + (size_t)N * NREL;
    float* w2  = h   + (size_t)N * HID;

    hipMemsetAsync(cnt, 0, (size_t)N * NREL * sizeof(float), stream);

    {   // h = root1 + bias1
        int NH = N * HID;
        init_h_kernel<<<(NH + 255) / 256, 256, 0, stream>>>(root1, bias1, h, NH);
    }
    {   // w2 = einsum('rb,bhc->rhc')
        int M = NREL * HID * NCLS;
        compute_w2_kernel<<<(M + 255) / 256, 256, 0, stream>>>(comp2, basis2, w2);
    }
    {   // cnt[(dst,rel)] counts
        count_kernel<<<(E + 255) / 256, 256, 0, stream>>>(dst, edge_type, cnt, E);
    }
    {   // layer-1 edge messages -> h
        long total = (long)E * 16;
        layer1_kernel<<<(int)((total + 255) / 256), 256, 0, stream>>>(
            src, dst, edge_type, comp1, basis1, cnt, h, E, N);
    }
    {   // out = h @ root2 + bias2
        out_init_kernel<<<(N + 255) / 256, 256, 0, stream>>>(h, root2, bias2, out, N);
    }
    {   // layer-2 edge messages -> out
        layer2_kernel<<<(E + 255) / 256, 256, 0, stream>>>(
            src, dst, edge_type, w2, cnt, h, out, E);
    }
}

// Round 2
// 1206.259 us; speedup vs baseline: 1.3836x; 1.3836x over previous
//
#include <hip/hip_runtime.h>

#define NREL   50
#define NBASE  30
#define HID    16
#define NCLS   8
#define SCAN_B 256

// ---------------- small setup kernels ----------------

__global__ void init_h_kernel(const float* __restrict__ root1,
                              const float* __restrict__ bias1,
                              float* __restrict__ h, int NH) {
    int i = blockIdx.x * blockDim.x + threadIdx.x;
    if (i < NH) h[i] = root1[i] + bias1[i & (HID - 1)];
}

__global__ void compute_w2_kernel(const float* __restrict__ comp2,
                                  const float* __restrict__ basis2,
                                  float* __restrict__ w2) {
    int i = blockIdx.x * blockDim.x + threadIdx.x;   // r*H*C + h*C + c
    if (i >= NREL * HID * NCLS) return;
    int r  = i / (HID * NCLS);
    int hc = i % (HID * NCLS);
    float acc = 0.f;
    #pragma unroll
    for (int b = 0; b < NBASE; ++b)
        acc += comp2[r * NBASE + b] * basis2[b * HID * NCLS + hc];
    w2[i] = acc;
}

__global__ void count_kernel(const int* __restrict__ dst,
                             const int* __restrict__ et,
                             float* __restrict__ cnt, int E) {
    int e = blockIdx.x * blockDim.x + threadIdx.x;
    if (e < E) atomicAdd(&cnt[dst[e] * NREL + et[e]], 1.0f);
}

// ---------------- counting sort by src ----------------

__global__ void hist_kernel(const int* __restrict__ src,
                            int* __restrict__ hist, int E) {
    int e = blockIdx.x * blockDim.x + threadIdx.x;
    if (e < E) atomicAdd(&hist[src[e]], 1);
}

// per-block exclusive scan of hist -> cur (exclusive-in-block), bsum[b]=block total
__global__ void scan1_kernel(const int* __restrict__ hist,
                             int* __restrict__ cur,
                             int* __restrict__ bsum, int N) {
    __shared__ int sh[SCAN_B];
    int tid = threadIdx.x;
    int i = blockIdx.x * SCAN_B + tid;
    int v = (i < N) ? hist[i] : 0;
    sh[tid] = v;
    __syncthreads();
    // Hillis-Steele inclusive scan
    #pragma unroll
    for (int off = 1; off < SCAN_B; off <<= 1) {
        int add = (tid >= off) ? sh[tid - off] : 0;
        __syncthreads();
        sh[tid] += add;
        __syncthreads();
    }
    if (i < N) cur[i] = sh[tid] - v;      // exclusive within block
    if (tid == SCAN_B - 1) bsum[blockIdx.x] = sh[tid];
}

// sequential exclusive scan of bsum (few hundred entries)
__global__ void scan2_kernel(int* __restrict__ bsum, int nb) {
    if (blockIdx.x == 0 && threadIdx.x == 0) {
        int run = 0;
        for (int i = 0; i < nb; ++i) {
            int t = bsum[i];
            bsum[i] = run;
            run += t;
        }
    }
}

__global__ void finalize_kernel(int* __restrict__ cur,
                                const int* __restrict__ bsum, int N) {
    int i = blockIdx.x * blockDim.x + threadIdx.x;
    if (i < N) cur[i] += bsum[i / SCAN_B];
}

// scatter edges into src-sorted order; also precompute inv_e
__global__ void scatter_kernel(const int* __restrict__ src,
                               const int* __restrict__ dst,
                               const int* __restrict__ et,
                               const float* __restrict__ cnt,
                               int* __restrict__ cur,
                               int* __restrict__ ssrc,
                               int* __restrict__ sdst,
                               int* __restrict__ stype,
                               float* __restrict__ sinv, int E) {
    int e = blockIdx.x * blockDim.x + threadIdx.x;
    if (e >= E) return;
    int s = src[e];
    int d = dst[e];
    int t = et[e];
    int pos = atomicAdd(&cur[s], 1);
    ssrc[pos]  = s;
    sdst[pos]  = d;
    stype[pos] = t;
    sinv[pos]  = 1.0f / cnt[d * NREL + t];
}

// ---------------- layer 1 (src-sorted) ----------------
// 16 threads per edge, one per hidden channel.
__global__ void layer1_kernel(const int* __restrict__ ssrc,
                              const int* __restrict__ sdst,
                              const int* __restrict__ stype,
                              const float* __restrict__ sinv,
                              const float* __restrict__ comp1,
                              const float* __restrict__ basis1,
                              float* __restrict__ h, int E, int N) {
    int idx = blockIdx.x * blockDim.x + threadIdx.x;
    int e = idx >> 4;
    if (e >= E) return;
    int hh = idx & 15;
    int s = ssrc[e];
    int d = sdst[e];
    int t = stype[e];
    float inv = sinv[e];
    const float* c1 = comp1 + t * NBASE;
    long base   = (long)s * HID + hh;
    long stride = (long)N * HID;
    float acc = 0.f;
    #pragma unroll
    for (int b = 0; b < NBASE; ++b)
        acc += c1[b] * basis1[base + (long)b * stride];
    atomicAdd(&h[d * HID + hh], inv * acc);
}

// ---------------- out = h @ root2 + bias2 ----------------
__global__ void out_init_kernel(const float* __restrict__ h,
                                const float* __restrict__ root2,
                                const float* __restrict__ bias2,
                                float* __restrict__ out, int N) {
    int n = blockIdx.x * blockDim.x + threadIdx.x;
    if (n >= N) return;
    float hr[HID];
    const float4* h4 = reinterpret_cast<const float4*>(h + (size_t)n * HID);
    #pragma unroll
    for (int i = 0; i < HID / 4; ++i) {
        float4 v = h4[i];
        hr[4 * i + 0] = v.x; hr[4 * i + 1] = v.y;
        hr[4 * i + 2] = v.z; hr[4 * i + 3] = v.w;
    }
    float acc[NCLS];
    #pragma unroll
    for (int c = 0; c < NCLS; ++c) acc[c] = bias2[c];
    #pragma unroll
    for (int i = 0; i < HID; ++i) {
        float hv = hr[i];
        #pragma unroll
        for (int c = 0; c < NCLS; ++c)
            acc[c] += hv * root2[i * NCLS + c];
    }
    #pragma unroll
    for (int c = 0; c < NCLS; ++c) out[(size_t)n * NCLS + c] = acc[c];
}

// ---------------- layer 2 (src-sorted edges) ----------------
__global__ void layer2_kernel(const int* __restrict__ ssrc,
                              const int* __restrict__ sdst,
                              const int* __restrict__ stype,
                              const float* __restrict__ sinv,
                              const float* __restrict__ w2,
                              const float* __restrict__ h,
                              float* __restrict__ out, int E) {
    int e = blockIdx.x * blockDim.x + threadIdx.x;
    if (e >= E) return;
    int s = ssrc[e];
    int d = sdst[e];
    int t = stype[e];
    float inv = sinv[e];
    const float* w = w2 + t * HID * NCLS;

    float hr[HID];
    const float4* h4 = reinterpret_cast<const float4*>(h + (size_t)s * HID);
    #pragma unroll
    for (int i = 0; i < HID / 4; ++i) {
        float4 v = h4[i];
        hr[4 * i + 0] = v.x; hr[4 * i + 1] = v.y;
        hr[4 * i + 2] = v.z; hr[4 * i + 3] = v.w;
    }
    float acc[NCLS] = {0.f, 0.f, 0.f, 0.f, 0.f, 0.f, 0.f, 0.f};
    #pragma unroll
    for (int i = 0; i < HID; ++i) {
        float hv = hr[i];
        #pragma unroll
        for (int c = 0; c < NCLS; ++c)
            acc[c] += hv * w[i * NCLS + c];
    }
    #pragma unroll
    for (int c = 0; c < NCLS; ++c)
        atomicAdd(&out[(size_t)d * NCLS + c], inv * acc[c]);
}

// ---------------- launch ----------------

extern "C" void kernel_launch(void* const* d_in, const int* in_sizes, int n_in,
                              void* d_out, int out_size, void* d_ws, size_t ws_size,
                              hipStream_t stream) {
    const int*   edge_index = (const int*)  d_in[0];   // [2,E]
    const int*   edge_type  = (const int*)  d_in[1];   // [E]
    const float* basis1     = (const float*)d_in[2];   // [B,N,H]
    const float* comp1      = (const float*)d_in[3];   // [R,B]
    const float* root1      = (const float*)d_in[4];   // [N,H]
    const float* bias1      = (const float*)d_in[5];   // [H]
    const float* basis2     = (const float*)d_in[6];   // [B,H,C]
    const float* comp2      = (const float*)d_in[7];   // [R,B]
    const float* root2      = (const float*)d_in[8];   // [H,C]
    const float* bias2      = (const float*)d_in[9];   // [C]
    float* out = (float*)d_out;

    const int E = in_sizes[1];
    const int N = in_sizes[4] / HID;
    const int nb = (N + SCAN_B - 1) / SCAN_B;
    const int* src = edge_index;
    const int* dst = edge_index + E;

    // workspace layout:
    // floats: cnt[N*R] | h[N*H] | w2[R*H*C] | sinv[E]
    // ints:   hist[N] | cur[N] | bsum[nb] | ssrc[E] | sdst[E] | stype[E]
    float* ws   = (float*)d_ws;
    float* cnt  = ws;
    float* h    = cnt  + (size_t)N * NREL;
    float* w2   = h    + (size_t)N * HID;
    float* sinv = w2   + NREL * HID * NCLS;
    int*   hist = (int*)(sinv + E);
    int*   cur  = hist + N;
    int*   bsum = cur  + N;
    int*   ssrc = bsum + nb;
    int*   sdst = ssrc + E;
    int*   stype= sdst + E;

    hipMemsetAsync(cnt,  0, (size_t)N * NREL * sizeof(float), stream);
    hipMemsetAsync(hist, 0, (size_t)N * sizeof(int), stream);

    {   // h = root1 + bias1
        int NH = N * HID;
        init_h_kernel<<<(NH + 255) / 256, 256, 0, stream>>>(root1, bias1, h, NH);
    }
    {   // w2 = einsum('rb,bhc->rhc')
        int M = NREL * HID * NCLS;
        compute_w2_kernel<<<(M + 255) / 256, 256, 0, stream>>>(comp2, basis2, w2);
    }
    {   // cnt[(dst,rel)] counts
        count_kernel<<<(E + 255) / 256, 256, 0, stream>>>(dst, edge_type, cnt, E);
    }
    {   // counting sort by src
        hist_kernel<<<(E + 255) / 256, 256, 0, stream>>>(src, hist, E);
        scan1_kernel<<<nb, SCAN_B, 0, stream>>>(hist, cur, bsum, N);
        scan2_kernel<<<1, 64, 0, stream>>>(bsum, nb);
        finalize_kernel<<<(N + 255) / 256, 256, 0, stream>>>(cur, bsum, N);
        scatter_kernel<<<(E + 255) / 256, 256, 0, stream>>>(
            src, dst, edge_type, cnt, cur, ssrc, sdst, stype, sinv, E);
    }
    {   // layer-1 edge messages -> h
        long total = (long)E * 16;
        layer1_kernel<<<(int)((total + 255) / 256), 256, 0, stream>>>(
            ssrc, sdst, stype, sinv, comp1, basis1, h, E, N);
    }
    {   // out = h @ root2 + bias2
        out_init_kernel<<<(N + 255) / 256, 256, 0, stream>>>(h, root2, bias2, out, N);
    }
    {   // layer-2 edge messages -> out
        layer2_kernel<<<(E + 255) / 256, 256, 0, stream>>>(
            ssrc, sdst, stype, sinv, w2, h, out, E);
    }
}

// Round 3
// 885.754 us; speedup vs baseline: 1.8843x; 1.3618x over previous
//
#include <hip/hip_runtime.h>

#define NREL   50
#define NBASE  30
#define HID    16
#define NCLS   8
#define SCAN_B 256

// ---------------- small setup kernels ----------------

__global__ void init_h_kernel(const float* __restrict__ root1,
                              const float* __restrict__ bias1,
                              float* __restrict__ h, int NH) {
    int i = blockIdx.x * blockDim.x + threadIdx.x;
    if (i < NH) h[i] = root1[i] + bias1[i & (HID - 1)];
}

__global__ void compute_w2_kernel(const float* __restrict__ comp2,
                                  const float* __restrict__ basis2,
                                  float* __restrict__ w2) {
    int i = blockIdx.x * blockDim.x + threadIdx.x;   // r*H*C + h*C + c
    if (i >= NREL * HID * NCLS) return;
    int r  = i / (HID * NCLS);
    int hc = i % (HID * NCLS);
    float acc = 0.f;
    #pragma unroll
    for (int b = 0; b < NBASE; ++b)
        acc += comp2[r * NBASE + b] * basis2[b * HID * NCLS + hc];
    w2[i] = acc;
}

// count (dst,rel) segments + histograms by src and dst (all int atomics)
__global__ void count3_kernel(const int* __restrict__ src,
                              const int* __restrict__ dst,
                              const int* __restrict__ et,
                              int* __restrict__ cnt,
                              int* __restrict__ hist_s,
                              int* __restrict__ hist_d, int E) {
    int e = blockIdx.x * blockDim.x + threadIdx.x;
    if (e >= E) return;
    int s = src[e], d = dst[e], t = et[e];
    atomicAdd(&cnt[d * NREL + t], 1);
    atomicAdd(&hist_s[s], 1);
    atomicAdd(&hist_d[d], 1);
}

// ---------------- scan (shared by both sorts) ----------------

__global__ void scan1_kernel(const int* __restrict__ hist,
                             int* __restrict__ excl,
                             int* __restrict__ bsum, int N) {
    __shared__ int sh[SCAN_B];
    int tid = threadIdx.x;
    int i = blockIdx.x * SCAN_B + tid;
    int v = (i < N) ? hist[i] : 0;
    sh[tid] = v;
    __syncthreads();
    #pragma unroll
    for (int off = 1; off < SCAN_B; off <<= 1) {
        int add = (tid >= off) ? sh[tid - off] : 0;
        __syncthreads();
        sh[tid] += add;
        __syncthreads();
    }
    if (i < N) excl[i] = sh[tid] - v;
    if (tid == SCAN_B - 1) bsum[blockIdx.x] = sh[tid];
}

__global__ void scan2_kernel(int* __restrict__ bsum, int nb) {
    if (blockIdx.x == 0 && threadIdx.x == 0) {
        int run = 0;
        for (int i = 0; i < nb; ++i) { int t = bsum[i]; bsum[i] = run; run += t; }
    }
}

__global__ void finalize_src_kernel(int* __restrict__ cur,
                                    const int* __restrict__ bsum, int N) {
    int i = blockIdx.x * blockDim.x + threadIdx.x;
    if (i < N) cur[i] += bsum[i / SCAN_B];
}

// rowptr gets pristine offsets (rowptr[N]=E); cur_d gets a mutable copy
__global__ void finalize_dst_kernel(int* __restrict__ rowptr,
                                    int* __restrict__ cur_d,
                                    const int* __restrict__ bsum, int N, int E) {
    int i = blockIdx.x * blockDim.x + threadIdx.x;
    if (i >= N) return;
    int v = rowptr[i] + bsum[i / SCAN_B];
    rowptr[i] = v;
    cur_d[i] = v;
    if (i == N - 1) rowptr[N] = E;
}

// scatter edges into BOTH orders; precompute inv_e.
// e1 (src-order): {src, type|(dst<<6), inv_bits, dst_rank}
// e2 (dst-order): {src|(type<<20), inv_bits}
__global__ void scatter_kernel(const int* __restrict__ src,
                               const int* __restrict__ dst,
                               const int* __restrict__ et,
                               const int* __restrict__ cnt,
                               int* __restrict__ cur_s,
                               int* __restrict__ cur_d,
                               int4* __restrict__ e1,
                               int2* __restrict__ e2, int E) {
    int e = blockIdx.x * blockDim.x + threadIdx.x;
    if (e >= E) return;
    int s = src[e], d = dst[e], t = et[e];
    int c = cnt[d * NREL + t];
    float inv = 1.0f / (float)(c > 0 ? c : 1);
    int ps = atomicAdd(&cur_s[s], 1);
    int pd = atomicAdd(&cur_d[d], 1);
    e1[ps] = make_int4(s, t | (d << 6), __float_as_int(inv), pd);
    e2[pd] = make_int2(s | (t << 20), __float_as_int(inv));
}

// ---------------- layer 1 ----------------
// phase A (src-sorted, atomic-free): msg[dst_rank][:] = inv * sum_b comp1[t,b]*basis1[b,src,:]
__global__ void layer1A_kernel(const int4* __restrict__ e1,
                               const float* __restrict__ comp1,
                               const float* __restrict__ basis1,
                               float* __restrict__ msg, int E, int N) {
    long idx = (long)blockIdx.x * blockDim.x + threadIdx.x;
    int e = (int)(idx >> 4);
    if (e >= E) return;
    int hh = (int)(idx & 15);
    int4 v = e1[e];
    int s = v.x;
    int t = v.y & 63;
    float inv = __int_as_float(v.z);
    int w = v.w;
    const float* c1 = comp1 + t * NBASE;
    long base   = (long)s * HID + hh;
    long stride = (long)N * HID;
    float acc = 0.f;
    #pragma unroll
    for (int b = 0; b < NBASE; ++b)
        acc += c1[b] * basis1[base + (long)b * stride];
    msg[(long)w * HID + hh] = inv * acc;
}

// fallback phase (if ws too small for msg buffer): atomics into h
__global__ void layer1_atomic_kernel(const int4* __restrict__ e1,
                                     const float* __restrict__ comp1,
                                     const float* __restrict__ basis1,
                                     float* __restrict__ h, int E, int N) {
    long idx = (long)blockIdx.x * blockDim.x + threadIdx.x;
    int e = (int)(idx >> 4);
    if (e >= E) return;
    int hh = (int)(idx & 15);
    int4 v = e1[e];
    int s = v.x;
    int t = v.y & 63;
    int d = v.y >> 6;
    float inv = __int_as_float(v.z);
    const float* c1 = comp1 + t * NBASE;
    long base   = (long)s * HID + hh;
    long stride = (long)N * HID;
    float acc = 0.f;
    #pragma unroll
    for (int b = 0; b < NBASE; ++b)
        acc += c1[b] * basis1[base + (long)b * stride];
    atomicAdd(&h[d * HID + hh], inv * acc);
}

// phase B: h[d] = sum of contiguous msg segment + root1[d] + bias1
__global__ void layer1B_kernel(const float* __restrict__ msg,
                               const int* __restrict__ rowptr,
                               const float* __restrict__ root1,
                               const float* __restrict__ bias1,
                               float* __restrict__ h, int N) {
    int d = blockIdx.x * blockDim.x + threadIdx.x;
    if (d >= N) return;
    int k0 = rowptr[d], k1 = rowptr[d + 1];
    float acc[HID];
    #pragma unroll
    for (int i = 0; i < HID; ++i) acc[i] = 0.f;
    for (int k = k0; k < k1; ++k) {
        const float4* m4 = reinterpret_cast<const float4*>(msg + (long)k * HID);
        #pragma unroll
        for (int q = 0; q < HID / 4; ++q) {
            float4 m = m4[q];
            acc[4 * q + 0] += m.x; acc[4 * q + 1] += m.y;
            acc[4 * q + 2] += m.z; acc[4 * q + 3] += m.w;
        }
    }
    const float4* r4 = reinterpret_cast<const float4*>(root1 + (size_t)d * HID);
    float4* h4 = reinterpret_cast<float4*>(h + (size_t)d * HID);
    #pragma unroll
    for (int q = 0; q < HID / 4; ++q) {
        float4 r = r4[q];
        float4 o;
        o.x = acc[4 * q + 0] + r.x + bias1[4 * q + 0];
        o.y = acc[4 * q + 1] + r.y + bias1[4 * q + 1];
        o.z = acc[4 * q + 2] + r.z + bias1[4 * q + 2];
        o.w = acc[4 * q + 3] + r.w + bias1[4 * q + 3];
        h4[q] = o;
    }
}

// ---------------- layer 2 (dst-CSR, atomic-free, fused root term) ----------------
__global__ void layer2_kernel(const int2* __restrict__ e2,
                              const int* __restrict__ rowptr,
                              const float* __restrict__ w2,
                              const float* __restrict__ h,
                              const float* __restrict__ root2,
                              const float* __restrict__ bias2,
                              float* __restrict__ out, int N) {
    int d = blockIdx.x * blockDim.x + threadIdx.x;
    if (d >= N) return;
    int k0 = rowptr[d], k1 = rowptr[d + 1];

    float acc[NCLS];
    #pragma unroll
    for (int c = 0; c < NCLS; ++c) acc[c] = bias2[c];

    // root term: h[d] @ root2
    {
        const float4* h4 = reinterpret_cast<const float4*>(h + (size_t)d * HID);
        #pragma unroll
        for (int q = 0; q < HID / 4; ++q) {
            float4 hv = h4[q];
            float hvv[4] = {hv.x, hv.y, hv.z, hv.w};
            #pragma unroll
            for (int j = 0; j < 4; ++j) {
                int i = 4 * q + j;
                #pragma unroll
                for (int c = 0; c < NCLS; ++c)
                    acc[c] += hvv[j] * root2[i * NCLS + c];
            }
        }
    }

    for (int k = k0; k < k1; ++k) {
        int2 v = e2[k];
        int s = v.x & 0xFFFFF;
        int t = v.x >> 20;
        float inv = __int_as_float(v.y);
        const float* w = w2 + t * HID * NCLS;
        const float4* h4 = reinterpret_cast<const float4*>(h + (size_t)s * HID);
        float tmp[NCLS];
        #pragma unroll
        for (int c = 0; c < NCLS; ++c) tmp[c] = 0.f;
        #pragma unroll
        for (int q = 0; q < HID / 4; ++q) {
            float4 hv = h4[q];
            float hvv[4] = {hv.x, hv.y, hv.z, hv.w};
            #pragma unroll
            for (int j = 0; j < 4; ++j) {
                int i = 4 * q + j;
                #pragma unroll
                for (int c = 0; c < NCLS; ++c)
                    tmp[c] += hvv[j] * w[i * NCLS + c];
            }
        }
        #pragma unroll
        for (int c = 0; c < NCLS; ++c) acc[c] += inv * tmp[c];
    }

    float4* o4 = reinterpret_cast<float4*>(out + (size_t)d * NCLS);
    o4[0] = make_float4(acc[0], acc[1], acc[2], acc[3]);
    o4[1] = make_float4(acc[4], acc[5], acc[6], acc[7]);
}

// ---------------- launch ----------------

extern "C" void kernel_launch(void* const* d_in, const int* in_sizes, int n_in,
                              void* d_out, int out_size, void* d_ws, size_t ws_size,
                              hipStream_t stream) {
    const int*   edge_index = (const int*)  d_in[0];   // [2,E]
    const int*   edge_type  = (const int*)  d_in[1];   // [E]
    const float* basis1     = (const float*)d_in[2];   // [B,N,H]
    const float* comp1      = (const float*)d_in[3];   // [R,B]
    const float* root1      = (const float*)d_in[4];   // [N,H]
    const float* bias1      = (const float*)d_in[5];   // [H]
    const float* basis2     = (const float*)d_in[6];   // [B,H,C]
    const float* comp2      = (const float*)d_in[7];   // [R,B]
    const float* root2      = (const float*)d_in[8];   // [H,C]
    const float* bias2      = (const float*)d_in[9];   // [C]
    float* out = (float*)d_out;

    const int E = in_sizes[1];
    const int N = in_sizes[4] / HID;
    const int nb = (N + SCAN_B - 1) / SCAN_B;
    const int* src = edge_index;
    const int* dst = edge_index + E;

    // ---- workspace layout (bytes, manual alignment) ----
    char* base = (char*)d_ws;
    size_t off = 0;
    auto alloc = [&](size_t bytes, size_t align) -> char* {
        off = (off + align - 1) & ~(align - 1);
        char* p = base + off;
        off += bytes;
        return p;
    };
    // contiguous zero region: cnt | hist_s | hist_d
    int*  cnt    = (int*)  alloc((size_t)N * NREL * 4, 4);
    int*  hist_s = (int*)  alloc((size_t)N * 4, 4);
    int*  hist_d = (int*)  alloc((size_t)N * 4, 4);
    size_t zero_bytes = (size_t)N * (NREL + 2) * 4;
    int*  cur_s  = (int*)  alloc((size_t)N * 4, 4);
    int*  cur_d  = (int*)  alloc((size_t)N * 4, 4);
    int*  rowptr = (int*)  alloc((size_t)(N + 1) * 4, 4);
    int*  bsum_s = (int*)  alloc((size_t)nb * 4, 4);
    int*  bsum_d = (int*)  alloc((size_t)nb * 4, 4);
    float* w2    = (float*)alloc((size_t)NREL * HID * NCLS * 4, 4);
    float* h     = (float*)alloc((size_t)N * HID * 4, 16);
    int4* e1     = (int4*) alloc((size_t)E * 16, 16);
    int2* e2     = (int2*) alloc((size_t)E * 8, 8);
    size_t off_no_msg = off;
    float* msg   = (float*)alloc((size_t)E * HID * 4, 16);
    bool use_msg = (off <= ws_size);
    (void)off_no_msg;

    hipMemsetAsync(cnt, 0, zero_bytes, stream);

    {   // w2 = einsum('rb,bhc->rhc')
        int M = NREL * HID * NCLS;
        compute_w2_kernel<<<(M + 255) / 256, 256, 0, stream>>>(comp2, basis2, w2);
    }
    {   // counts + histograms
        count3_kernel<<<(E + 255) / 256, 256, 0, stream>>>(
            src, dst, edge_type, cnt, hist_s, hist_d, E);
    }
    {   // scan src
        scan1_kernel<<<nb, SCAN_B, 0, stream>>>(hist_s, cur_s, bsum_s, N);
        scan2_kernel<<<1, 64, 0, stream>>>(bsum_s, nb);
        finalize_src_kernel<<<(N + 255) / 256, 256, 0, stream>>>(cur_s, bsum_s, N);
    }
    {   // scan dst -> rowptr + cur_d
        scan1_kernel<<<nb, SCAN_B, 0, stream>>>(hist_d, rowptr, bsum_d, N);
        scan2_kernel<<<1, 64, 0, stream>>>(bsum_d, nb);
        finalize_dst_kernel<<<(N + 255) / 256, 256, 0, stream>>>(rowptr, cur_d, bsum_d, N, E);
    }
    {   // scatter into both orders
        scatter_kernel<<<(E + 255) / 256, 256, 0, stream>>>(
            src, dst, edge_type, cnt, cur_s, cur_d, e1, e2, E);
    }

    if (use_msg) {
        long total = (long)E * 16;
        layer1A_kernel<<<(int)((total + 255) / 256), 256, 0, stream>>>(
            e1, comp1, basis1, msg, E, N);
        layer1B_kernel<<<(N + 255) / 256, 256, 0, stream>>>(
            msg, rowptr, root1, bias1, h, N);
    } else {
        int NH = N * HID;
        init_h_kernel<<<(NH + 255) / 256, 256, 0, stream>>>(root1, bias1, h, NH);
        long total = (long)E * 16;
        layer1_atomic_kernel<<<(int)((total + 255) / 256), 256, 0, stream>>>(
            e1, comp1, basis1, h, E, N);
    }

    {   // layer 2: dst-CSR, fused root term, single write per node
        layer2_kernel<<<(N + 255) / 256, 256, 0, stream>>>(
            e2, rowptr, w2, h, root2, bias2, out, N);
    }
}

// Round 4
// 844.231 us; speedup vs baseline: 1.9770x; 1.0492x over previous
//
#include <hip/hip_runtime.h>

#define NREL   50
#define NBASE  30
#define HID    16
#define NCLS   8
#define SCAN_B 256
#define TPN    32
#define TPSTRIDE 484          // 30*16 + 4 pad (floats)
#define W2T    56             // padded t-stride for w2 LDS ([hc][t] layout)

// ---------------- small setup kernels ----------------

__global__ void compute_w2_kernel(const float* __restrict__ comp2,
                                  const float* __restrict__ basis2,
                                  float* __restrict__ w2) {
    int i = blockIdx.x * blockDim.x + threadIdx.x;   // r*H*C + h*C + c
    if (i >= NREL * HID * NCLS) return;
    int r  = i / (HID * NCLS);
    int hc = i % (HID * NCLS);
    float acc = 0.f;
    #pragma unroll
    for (int b = 0; b < NBASE; ++b)
        acc += comp2[r * NBASE + b] * basis2[b * HID * NCLS + hc];
    w2[i] = acc;
}

// count (dst,rel) segments + src histogram
__global__ void count2_kernel(const int* __restrict__ src,
                              const int* __restrict__ dst,
                              const int* __restrict__ et,
                              int* __restrict__ cnt,
                              int* __restrict__ hist_s, int E) {
    int e = blockIdx.x * blockDim.x + threadIdx.x;
    if (e >= E) return;
    atomicAdd(&cnt[dst[e] * NREL + et[e]], 1);
    atomicAdd(&hist_s[src[e]], 1);
}

// hist_d[d] = sum_t cnt[d][t]
__global__ void histd_kernel(const int* __restrict__ cnt,
                             int* __restrict__ hist_d, int N) {
    int d = blockIdx.x * blockDim.x + threadIdx.x;
    if (d >= N) return;
    const int2* row = reinterpret_cast<const int2*>(cnt + (size_t)d * NREL);
    int s = 0;
    #pragma unroll
    for (int i = 0; i < NREL / 2; ++i) { int2 v = row[i]; s += v.x + v.y; }
    hist_d[d] = s;
}

// ---------------- scans ----------------

__global__ void scan1_kernel(const int* __restrict__ hist,
                             int* __restrict__ excl,
                             int* __restrict__ bsum, int N) {
    __shared__ int sh[SCAN_B];
    int tid = threadIdx.x;
    int i = blockIdx.x * SCAN_B + tid;
    int v = (i < N) ? hist[i] : 0;
    sh[tid] = v;
    __syncthreads();
    #pragma unroll
    for (int off = 1; off < SCAN_B; off <<= 1) {
        int add = (tid >= off) ? sh[tid - off] : 0;
        __syncthreads();
        sh[tid] += add;
        __syncthreads();
    }
    if (i < N) excl[i] = sh[tid] - v;
    if (tid == SCAN_B - 1) bsum[blockIdx.x] = sh[tid];
}

// single-block exclusive scan of bsum (nb <= 1024)
__global__ void scan2_block_kernel(int* __restrict__ bsum, int nb) {
    __shared__ int sh[1024];
    int tid = threadIdx.x;
    int v = (tid < nb) ? bsum[tid] : 0;
    sh[tid] = v;
    __syncthreads();
    #pragma unroll
    for (int off = 1; off < 1024; off <<= 1) {
        int add = (tid >= off) ? sh[tid - off] : 0;
        __syncthreads();
        sh[tid] += add;
        __syncthreads();
    }
    if (tid < nb) bsum[tid] = sh[tid] - v;
}

__global__ void scan2_serial_kernel(int* __restrict__ bsum, int nb) {
    if (blockIdx.x == 0 && threadIdx.x == 0) {
        int run = 0;
        for (int i = 0; i < nb; ++i) { int t = bsum[i]; bsum[i] = run; run += t; }
    }
}

__global__ void finalize_src_kernel(int* __restrict__ cur,
                                    const int* __restrict__ bsum, int N) {
    int i = blockIdx.x * blockDim.x + threadIdx.x;
    if (i < N) cur[i] += bsum[i / SCAN_B];
}

__global__ void finalize_dst_kernel(int* __restrict__ rowptr,
                                    int* __restrict__ cur_d,
                                    const int* __restrict__ bsum, int N, int E) {
    int i = blockIdx.x * blockDim.x + threadIdx.x;
    if (i >= N) return;
    int v = rowptr[i] + bsum[i / SCAN_B];
    rowptr[i] = v;
    cur_d[i] = v;
    if (i == N - 1) rowptr[N] = E;
}

// scatter edges into both orders.
// e1 (src-order): {s | t<<20, dst_rank}; e2 (dst-order): s | t<<20
__global__ void scatter_kernel(const int* __restrict__ src,
                               const int* __restrict__ dst,
                               const int* __restrict__ et,
                               int* __restrict__ cur_s,
                               int* __restrict__ cur_d,
                               int2* __restrict__ e1,
                               int* __restrict__ e2, int E) {
    int e = blockIdx.x * blockDim.x + threadIdx.x;
    if (e >= E) return;
    int s = src[e], d = dst[e], t = et[e];
    int packed = s | (t << 20);
    int ps = atomicAdd(&cur_s[s], 1);
    int pd = atomicAdd(&cur_d[d], 1);
    e1[ps] = make_int2(packed, pd);
    e2[pd] = packed;
}

// ---------------- basis1 transpose [B,N,H] -> [N,B,H] ----------------
__global__ void transpose_kernel(const float* __restrict__ in,
                                 float* __restrict__ outp, int N) {
    __shared__ float tile[TPN * TPSTRIDE];
    int n0 = blockIdx.x * TPN;
    for (int i = threadIdx.x; i < NBASE * TPN * 4; i += blockDim.x) {
        int b = i / (TPN * 4);
        int r = i % (TPN * 4);
        int n = r >> 2, q = r & 3;
        if (n0 + n < N) {
            float4 v = *reinterpret_cast<const float4*>(
                in + ((long)b * N + n0 + n) * HID + q * 4);
            *reinterpret_cast<float4*>(tile + n * TPSTRIDE + b * HID + q * 4) = v;
        }
    }
    __syncthreads();
    for (int i = threadIdx.x; i < TPN * NBASE * 4; i += blockDim.x) {
        int n = i / (NBASE * 4);
        int r = i % (NBASE * 4);
        if (n0 + n < N) {
            float4 v = *reinterpret_cast<const float4*>(tile + n * TPSTRIDE + r * 4);
            *reinterpret_cast<float4*>(
                outp + (long)(n0 + n) * NBASE * HID + r * 4) = v;
        }
    }
}

// ---------------- layer 1 phase A ----------------
// 4 threads/edge (one h-quad each). msg[dst_rank] = sum_b comp1[t,b]*basis[s,b,:]
// (inv applied in phase B). Strides parameterized for transposed/fallback layout.
__global__ void layer1A_kernel(const int2* __restrict__ e1,
                               const float* __restrict__ comp1,
                               const float* __restrict__ basis,
                               long sn, long sb,
                               float* __restrict__ msg, int E) {
    __shared__ float c1s[NREL * NBASE];
    for (int i = threadIdx.x; i < NREL * NBASE; i += blockDim.x)
        c1s[i] = comp1[i];
    __syncthreads();

    long idx = (long)blockIdx.x * blockDim.x + threadIdx.x;
    int e = (int)(idx >> 2);
    if (e >= E) return;
    int q = (int)(idx & 3);
    int2 v = e1[e];
    int s = v.x & 0xFFFFF;
    int t = ((unsigned)v.x) >> 20;
    int w = v.y;
    const float* cr = c1s + t * NBASE;
    const float* bp = basis + (long)s * sn + q * 4;

    float4 acc = make_float4(0.f, 0.f, 0.f, 0.f);
    #pragma unroll
    for (int b = 0; b < NBASE; ++b) {
        float4 x = *reinterpret_cast<const float4*>(bp + b * sb);
        float c = cr[b];
        acc.x += c * x.x; acc.y += c * x.y;
        acc.z += c * x.z; acc.w += c * x.w;
    }
    *reinterpret_cast<float4*>(msg + (long)w * HID + q * 4) = acc;
}

// ---------------- layer 1 phase B ----------------
// thread per (node, h-quad): h[d] = sum_k inv_k*msg_k + root1[d] + bias1
__global__ void layer1B_kernel(const float* __restrict__ msg,
                               const int* __restrict__ e2,
                               const int* __restrict__ rowptr,
                               const int* __restrict__ cnt,
                               const float* __restrict__ root1,
                               const float* __restrict__ bias1,
                               float* __restrict__ h, int N) {
    int gid = blockIdx.x * blockDim.x + threadIdx.x;
    int d = gid >> 2;
    if (d >= N) return;
    int q = gid & 3;
    int k0 = rowptr[d], k1 = rowptr[d + 1];
    const int* crow = cnt + (size_t)d * NREL;
    float4 acc = make_float4(0.f, 0.f, 0.f, 0.f);
    for (int k = k0; k < k1; ++k) {
        int t = ((unsigned)e2[k]) >> 20;
        float inv = 1.0f / (float)crow[t];
        float4 m = *reinterpret_cast<const float4*>(msg + (long)k * HID + q * 4);
        acc.x += inv * m.x; acc.y += inv * m.y;
        acc.z += inv * m.z; acc.w += inv * m.w;
    }
    float4 r = *reinterpret_cast<const float4*>(root1 + (size_t)d * HID + q * 4);
    float4 bv = *reinterpret_cast<const float4*>(bias1 + q * 4);
    float4 o;
    o.x = acc.x + r.x + bv.x; o.y = acc.y + r.y + bv.y;
    o.z = acc.z + r.z + bv.z; o.w = acc.w + r.w + bv.w;
    *reinterpret_cast<float4*>(h + (size_t)d * HID + q * 4) = o;
}

// ---------------- layer 2 ----------------
// 4 threads per node (k-split), w2 staged in LDS [hc][t] (scalar, conflict-light),
// shfl_xor reduce, fused root term, single write per node.
__global__ void layer2_kernel(const int* __restrict__ e2,
                              const int* __restrict__ rowptr,
                              const int* __restrict__ cnt,
                              const float* __restrict__ w2,
                              const float* __restrict__ h,
                              const float* __restrict__ root2,
                              const float* __restrict__ bias2,
                              float* __restrict__ out, int N) {
    __shared__ float w2s[HID * NCLS * W2T];
    for (int i = threadIdx.x; i < NREL * HID * NCLS; i += blockDim.x) {
        int t = i / (HID * NCLS);
        int hc = i % (HID * NCLS);
        w2s[hc * W2T + t] = w2[i];
    }
    __syncthreads();

    int gid = blockIdx.x * blockDim.x + threadIdx.x;
    int d = gid >> 2;
    if (d >= N) return;
    int q = gid & 3;
    int k0 = rowptr[d], k1 = rowptr[d + 1];
    const int* crow = cnt + (size_t)d * NREL;

    float acc[NCLS];
    #pragma unroll
    for (int c = 0; c < NCLS; ++c) acc[c] = 0.f;

    for (int k = k0 + q; k < k1; k += 4) {
        int v = e2[k];
        int s = v & 0xFFFFF;
        int t = ((unsigned)v) >> 20;
        float inv = 1.0f / (float)crow[t];
        const float4* h4 = reinterpret_cast<const float4*>(h + (size_t)s * HID);
        float tmp[NCLS];
        #pragma unroll
        for (int c = 0; c < NCLS; ++c) tmp[c] = 0.f;
        #pragma unroll
        for (int p = 0; p < HID / 4; ++p) {
            float4 hv = h4[p];
            float hvv[4] = {hv.x, hv.y, hv.z, hv.w};
            #pragma unroll
            for (int j = 0; j < 4; ++j) {
                int i = 4 * p + j;
                #pragma unroll
                for (int c = 0; c < NCLS; ++c)
                    tmp[c] += hvv[j] * w2s[(i * NCLS + c) * W2T + t];
            }
        }
        #pragma unroll
        for (int c = 0; c < NCLS; ++c) acc[c] += inv * tmp[c];
    }

    // reduce across the 4 lanes of this node
    #pragma unroll
    for (int c = 0; c < NCLS; ++c) {
        acc[c] += __shfl_xor(acc[c], 1);
        acc[c] += __shfl_xor(acc[c], 2);
    }

    if (q == 0) {
        // root term + bias
        const float4* h4 = reinterpret_cast<const float4*>(h + (size_t)d * HID);
        #pragma unroll
        for (int p = 0; p < HID / 4; ++p) {
            float4 hv = h4[p];
            float hvv[4] = {hv.x, hv.y, hv.z, hv.w};
            #pragma unroll
            for (int j = 0; j < 4; ++j) {
                int i = 4 * p + j;
                #pragma unroll
                for (int c = 0; c < NCLS; ++c)
                    acc[c] += hvv[j] * root2[i * NCLS + c];
            }
        }
        #pragma unroll
        for (int c = 0; c < NCLS; ++c) acc[c] += bias2[c];
        float4* o4 = reinterpret_cast<float4*>(out + (size_t)d * NCLS);
        o4[0] = make_float4(acc[0], acc[1], acc[2], acc[3]);
        o4[1] = make_float4(acc[4], acc[5], acc[6], acc[7]);
    }
}

// ---------------- launch ----------------

extern "C" void kernel_launch(void* const* d_in, const int* in_sizes, int n_in,
                              void* d_out, int out_size, void* d_ws, size_t ws_size,
                              hipStream_t stream) {
    const int*   edge_index = (const int*)  d_in[0];
    const int*   edge_type  = (const int*)  d_in[1];
    const float* basis1     = (const float*)d_in[2];
    const float* comp1      = (const float*)d_in[3];
    const float* root1      = (const float*)d_in[4];
    const float* bias1      = (const float*)d_in[5];
    const float* basis2     = (const float*)d_in[6];
    const float* comp2      = (const float*)d_in[7];
    const float* root2      = (const float*)d_in[8];
    const float* bias2      = (const float*)d_in[9];
    float* out = (float*)d_out;

    const int E = in_sizes[1];
    const int N = in_sizes[4] / HID;
    const int nb = (N + SCAN_B - 1) / SCAN_B;
    const int* src = edge_index;
    const int* dst = edge_index + E;

    char* base = (char*)d_ws;
    size_t off = 0;
    auto alloc = [&](size_t bytes, size_t align) -> char* {
        off = (off + align - 1) & ~(align - 1);
        char* p = base + off;
        off += bytes;
        return p;
    };
    // contiguous zero region: cnt | hist_s
    int*  cnt    = (int*)  alloc((size_t)N * NREL * 4, 4);
    int*  hist_s = (int*)  alloc((size_t)N * 4, 4);
    size_t zero_bytes = (size_t)N * (NREL + 1) * 4;
    int*  hist_d = (int*)  alloc((size_t)N * 4, 4);
    int*  cur_s  = (int*)  alloc((size_t)N * 4, 4);
    int*  cur_d  = (int*)  alloc((size_t)N * 4, 4);
    int*  rowptr = (int*)  alloc((size_t)(N + 1) * 4, 4);
    int*  bsum_s = (int*)  alloc((size_t)nb * 4, 4);
    int*  bsum_d = (int*)  alloc((size_t)nb * 4, 4);
    float* w2    = (float*)alloc((size_t)NREL * HID * NCLS * 4, 16);
    float* h     = (float*)alloc((size_t)N * HID * 4, 16);
    int2* e1     = (int2*) alloc((size_t)E * 8, 8);
    int*  e2     = (int*)  alloc((size_t)E * 4, 4);
    float* msg   = (float*)alloc((size_t)E * HID * 4, 16);
    float* b1t   = (float*)alloc((size_t)N * NBASE * HID * 4, 16);
    bool use_t = (off <= ws_size);

    hipMemsetAsync(cnt, 0, zero_bytes, stream);

    {   int M = NREL * HID * NCLS;
        compute_w2_kernel<<<(M + 255) / 256, 256, 0, stream>>>(comp2, basis2, w2);
    }
    count2_kernel<<<(E + 255) / 256, 256, 0, stream>>>(src, dst, edge_type, cnt, hist_s, E);
    histd_kernel<<<(N + 255) / 256, 256, 0, stream>>>(cnt, hist_d, N);

    {   // scan src -> cur_s
        scan1_kernel<<<nb, SCAN_B, 0, stream>>>(hist_s, cur_s, bsum_s, N);
        if (nb <= 1024) scan2_block_kernel<<<1, 1024, 0, stream>>>(bsum_s, nb);
        else            scan2_serial_kernel<<<1, 64, 0, stream>>>(bsum_s, nb);
        finalize_src_kernel<<<(N + 255) / 256, 256, 0, stream>>>(cur_s, bsum_s, N);
    }
    {   // scan dst -> rowptr + cur_d
        scan1_kernel<<<nb, SCAN_B, 0, stream>>>(hist_d, rowptr, bsum_d, N);
        if (nb <= 1024) scan2_block_kernel<<<1, 1024, 0, stream>>>(bsum_d, nb);
        else            scan2_serial_kernel<<<1, 64, 0, stream>>>(bsum_d, nb);
        finalize_dst_kernel<<<(N + 255) / 256, 256, 0, stream>>>(rowptr, cur_d, bsum_d, N, E);
    }
    scatter_kernel<<<(E + 255) / 256, 256, 0, stream>>>(
        src, dst, edge_type, cur_s, cur_d, e1, e2, E);

    long sn, sb;
    const float* bptr;
    if (use_t) {
        transpose_kernel<<<(N + TPN - 1) / TPN, 256, 0, stream>>>(basis1, b1t, N);
        bptr = b1t; sn = NBASE * HID; sb = HID;
    } else {
        bptr = basis1; sn = HID; sb = (long)N * HID;
    }

    {   long total = (long)E * 4;
        layer1A_kernel<<<(int)((total + 255) / 256), 256, 0, stream>>>(
            e1, comp1, bptr, sn, sb, msg, E);
    }
    {   long total = (long)N * 4;
        layer1B_kernel<<<(int)((total + 255) / 256), 256, 0, stream>>>(
            msg, e2, rowptr, cnt, root1, bias1, h, N);
    }
    {   long total = (long)N * 4;
        layer2_kernel<<<(int)((total + 255) / 256), 256, 0, stream>>>(
            e2, rowptr, cnt, w2, h, root2, bias2, out, N);
    }
}

// Round 5
// 724.644 us; speedup vs baseline: 2.3032x; 1.1650x over previous
//
#include <hip/hip_runtime.h>

#define NREL   50
#define NBASE  30
#define HID    16
#define NCLS   8

#define SHIFT   9
#define BWID    (1 << SHIFT)       // 512 nodes per bucket
#define NBUKMAX 512                // supports N <= 262144
#define TILE    4096               // edges per scatter block
#define EPB     16                 // edges per thread (256 threads)
#define W2T     56                 // padded t-stride for w2 LDS

// ---------------- setup ----------------

__global__ void compute_w2_kernel(const float* __restrict__ comp2,
                                  const float* __restrict__ basis2,
                                  float* __restrict__ w2) {
    int i = blockIdx.x * blockDim.x + threadIdx.x;
    if (i >= NREL * HID * NCLS) return;
    int r  = i / (HID * NCLS);
    int hc = i % (HID * NCLS);
    float acc = 0.f;
    #pragma unroll
    for (int b = 0; b < NBASE; ++b)
        acc += comp2[r * NBASE + b] * basis2[b * HID * NCLS + hc];
    w2[i] = acc;
}

// ---------------- bucket histograms (LDS-privatized) ----------------

__global__ void ghist_kernel(const int* __restrict__ src,
                             const int* __restrict__ dst,
                             int* __restrict__ hs, int* __restrict__ hd,
                             int E, int nbuk) {
    __shared__ int lhs[NBUKMAX], lhd[NBUKMAX];
    for (int j = threadIdx.x; j < nbuk; j += blockDim.x) { lhs[j] = 0; lhd[j] = 0; }
    __syncthreads();
    for (long e = (long)blockIdx.x * blockDim.x + threadIdx.x; e < E;
         e += (long)gridDim.x * blockDim.x) {
        atomicAdd(&lhs[src[e] >> SHIFT], 1);
        atomicAdd(&lhd[dst[e] >> SHIFT], 1);
    }
    __syncthreads();
    for (int j = threadIdx.x; j < nbuk; j += blockDim.x) {
        if (lhs[j]) atomicAdd(&hs[j], lhs[j]);
        if (lhd[j]) atomicAdd(&hd[j], lhd[j]);
    }
}

// exclusive scans of both histograms (LDS-staged, thread0 serial over <=512)
__global__ void scanbuk_kernel(const int* __restrict__ hs, const int* __restrict__ hd,
                               int* __restrict__ gcs, int* __restrict__ based,
                               int* __restrict__ gcd, int nbuk, int E) {
    __shared__ int a[NBUKMAX], b[NBUKMAX];
    int tid = threadIdx.x;
    for (int j = tid; j < nbuk; j += blockDim.x) { a[j] = hs[j]; b[j] = hd[j]; }
    __syncthreads();
    if (tid == 0) {
        int run = 0;
        for (int i = 0; i < nbuk; ++i) { int v = a[i]; a[i] = run; run += v; }
        run = 0;
        for (int i = 0; i < nbuk; ++i) { int v = b[i]; b[i] = run; run += v; }
    }
    __syncthreads();
    for (int j = tid; j < nbuk; j += blockDim.x) {
        gcs[j] = a[j]; based[j] = b[j]; gcd[j] = b[j];
    }
    if (tid == 0) based[nbuk] = E;
}

// ---------------- pass 1: bucket-sort by src>>SHIFT ----------------
// A[pos] = {s | t<<17, d}; per-block LDS hist -> one global claim per bucket.
__global__ void pass1_kernel(const int* __restrict__ src,
                             const int* __restrict__ dst,
                             const int* __restrict__ et,
                             int* __restrict__ gcur, int2* __restrict__ A, int E) {
    __shared__ int lhist[NBUKMAX], lbase[NBUKMAX], lcur[NBUKMAX];
    int tid = threadIdx.x;
    for (int j = tid; j < NBUKMAX; j += 256) { lhist[j] = 0; lcur[j] = 0; }
    __syncthreads();
    int2 p[EPB]; int bk[EPB];
    long e0 = (long)blockIdx.x * TILE;
    #pragma unroll
    for (int j = 0; j < EPB; ++j) {
        long e = e0 + j * 256 + tid;
        if (e < E) {
            int s = src[e], d = dst[e], t = et[e];
            p[j] = make_int2(s | (t << 17), d);
            bk[j] = s >> SHIFT;
            atomicAdd(&lhist[bk[j]], 1);
        } else bk[j] = -1;
    }
    __syncthreads();
    for (int j = tid; j < NBUKMAX; j += 256)
        if (lhist[j] > 0) lbase[j] = atomicAdd(&gcur[j], lhist[j]);
    __syncthreads();
    #pragma unroll
    for (int j = 0; j < EPB; ++j) {
        if (bk[j] >= 0) {
            int r = atomicAdd(&lcur[bk[j]], 1);
            A[lbase[bk[j]] + r] = p[j];
        }
    }
}

// ---------------- pass 2: bucket-sort A by dst>>SHIFT ----------------
// B[pos] = {s|t<<17, psi | dlow<<21}, psi = index into A (= msg row).
__global__ void pass2_kernel(const int2* __restrict__ A,
                             int* __restrict__ gcur, int2* __restrict__ B, int E) {
    __shared__ int lhist[NBUKMAX], lbase[NBUKMAX], lcur[NBUKMAX];
    int tid = threadIdx.x;
    for (int j = tid; j < NBUKMAX; j += 256) { lhist[j] = 0; lcur[j] = 0; }
    __syncthreads();
    int2 p[EPB]; int bk[EPB];
    long e0 = (long)blockIdx.x * TILE;
    #pragma unroll
    for (int j = 0; j < EPB; ++j) {
        long e = e0 + j * 256 + tid;
        if (e < E) {
            int2 a = A[e];
            int d = a.y;
            p[j] = make_int2(a.x, (int)e | ((d & (BWID - 1)) << 21));
            bk[j] = d >> SHIFT;
            atomicAdd(&lhist[bk[j]], 1);
        } else bk[j] = -1;
    }
    __syncthreads();
    for (int j = tid; j < NBUKMAX; j += 256)
        if (lhist[j] > 0) lbase[j] = atomicAdd(&gcur[j], lhist[j]);
    __syncthreads();
    #pragma unroll
    for (int j = 0; j < EPB; ++j) {
        if (bk[j] >= 0) {
            int r = atomicAdd(&lcur[bk[j]], 1);
            B[lbase[bk[j]] + r] = p[j];
        }
    }
}

// ---------------- pass 3: exact dst grouping within each bucket ----------------
// One block per dst-bucket; writes stay inside the bucket's own output window.
__global__ void pass3_kernel(const int2* __restrict__ B,
                             const int* __restrict__ based,
                             int2* __restrict__ e2, int* __restrict__ rowptr,
                             int N, int E) {
    __shared__ int lh[NBUKMAX], sA[NBUKMAX], sB[NBUKMAX];
    int blk = blockIdx.x, tid = threadIdx.x;
    int k0 = based[blk], k1 = based[blk + 1], cnt = k1 - k0;
    for (int j = tid; j < NBUKMAX; j += 256) lh[j] = 0;
    __syncthreads();
    for (int i = tid; i < cnt; i += 256) {
        int dlow = ((unsigned)B[k0 + i].y) >> 21;
        atomicAdd(&lh[dlow], 1);
    }
    __syncthreads();
    for (int j = tid; j < NBUKMAX; j += 256) sA[j] = lh[j];
    __syncthreads();
    int* cur = sA; int* oth = sB;
    for (int off = 1; off < NBUKMAX; off <<= 1) {
        for (int j = tid; j < NBUKMAX; j += 256)
            oth[j] = cur[j] + (j >= off ? cur[j - off] : 0);
        __syncthreads();
        int* t_ = cur; cur = oth; oth = t_;
    }
    // cur = inclusive scan; exclusive = cur[j]-lh[j]; reuse oth as cursor
    for (int j = tid; j < NBUKMAX; j += 256) {
        int excl = cur[j] - lh[j];
        oth[j] = excl;
        int d = blk * BWID + j;
        if (d < N) rowptr[d] = k0 + excl;
    }
    __syncthreads();
    for (int i = tid; i < cnt; i += 256) {
        int2 b = B[k0 + i];
        int dlow = ((unsigned)b.y) >> 21;
        int pos = atomicAdd(&oth[dlow], 1);
        e2[k0 + pos] = make_int2(b.x, b.y & 0x1FFFFF);
    }
    if (blk == 0 && tid == 0) rowptr[N] = E;
}

// ---------------- layer 1 phase A (edge-centric over src-bucketed A) ----------------
// 4 lanes/edge; basis1 in ORIGINAL [B,N,H] layout (bucket window is L2-resident);
// msg written sequentially at the edge's A-index.
__global__ void layer1A_kernel(const int2* __restrict__ A,
                               const float* __restrict__ comp1,
                               const float* __restrict__ basis1,
                               float* __restrict__ msg, int E, int N) {
    __shared__ float c1s[NREL * NBASE];
    for (int i = threadIdx.x; i < NREL * NBASE; i += blockDim.x)
        c1s[i] = comp1[i];
    __syncthreads();
    long idx = (long)blockIdx.x * blockDim.x + threadIdx.x;
    long e = idx >> 2;
    if (e >= E) return;
    int q = (int)(idx & 3);
    int sx = A[e].x;
    int s = sx & 0x1FFFF;
    int t = ((unsigned)sx) >> 17;
    const float* cr = c1s + t * NBASE;
    const float* bp = basis1 + (long)s * HID + q * 4;
    long stride = (long)N * HID;
    float4 acc = make_float4(0.f, 0.f, 0.f, 0.f);
    #pragma unroll
    for (int b = 0; b < NBASE; ++b) {
        float4 x = *reinterpret_cast<const float4*>(bp + b * stride);
        float c = cr[b];
        acc.x += c * x.x; acc.y += c * x.y;
        acc.z += c * x.z; acc.w += c * x.w;
    }
    *reinterpret_cast<float4*>(msg + e * HID + q * 4) = acc;
}

// ---------------- layer 1 phase B ----------------
// thread per dst node: inv via O(deg^2) segment scan (L1-resident), gather msg
// rows (full 64B lines), + root1 + bias1 -> h; store sinv for layer2.
__global__ void layer1B_kernel(const int2* __restrict__ e2,
                               const int* __restrict__ rowptr,
                               const float* __restrict__ msg,
                               const float* __restrict__ root1,
                               const float* __restrict__ bias1,
                               float* __restrict__ h, float* __restrict__ sinv, int N) {
    int d = blockIdx.x * blockDim.x + threadIdx.x;
    if (d >= N) return;
    int k0 = rowptr[d], k1 = rowptr[d + 1];
    float acc[HID];
    #pragma unroll
    for (int i = 0; i < HID; ++i) acc[i] = 0.f;
    for (int k = k0; k < k1; ++k) {
        int2 v = e2[k];
        unsigned t = ((unsigned)v.x) >> 17;
        int c = 0;
        for (int j = k0; j < k1; ++j)
            c += ((((unsigned)e2[j].x) >> 17) == t);
        float inv = 1.0f / (float)c;
        sinv[k] = inv;
        const float4* m4 = reinterpret_cast<const float4*>(msg + (long)v.y * HID);
        #pragma unroll
        for (int p = 0; p < HID / 4; ++p) {
            float4 m = m4[p];
            acc[4 * p + 0] += inv * m.x; acc[4 * p + 1] += inv * m.y;
            acc[4 * p + 2] += inv * m.z; acc[4 * p + 3] += inv * m.w;
        }
    }
    float4* h4 = reinterpret_cast<float4*>(h + (size_t)d * HID);
    #pragma unroll
    for (int p = 0; p < HID / 4; ++p) {
        float4 r = *reinterpret_cast<const float4*>(root1 + (size_t)d * HID + p * 4);
        float4 bv = *reinterpret_cast<const float4*>(bias1 + p * 4);
        h4[p] = make_float4(acc[4 * p + 0] + r.x + bv.x,
                            acc[4 * p + 1] + r.y + bv.y,
                            acc[4 * p + 2] + r.z + bv.z,
                            acc[4 * p + 3] + r.w + bv.w);
    }
}

// ---------------- layer 2 ----------------
// 4 threads/node (k-split), w2 in LDS [hc][t], shfl reduce, fused root term.
__global__ void layer2_kernel(const int2* __restrict__ e2,
                              const int* __restrict__ rowptr,
                              const float* __restrict__ sinv,
                              const float* __restrict__ w2,
                              const float* __restrict__ h,
                              const float* __restrict__ root2,
                              const float* __restrict__ bias2,
                              float* __restrict__ out, int N) {
    __shared__ float w2s[HID * NCLS * W2T];
    for (int i = threadIdx.x; i < NREL * HID * NCLS; i += blockDim.x) {
        int t = i / (HID * NCLS);
        int hc = i % (HID * NCLS);
        w2s[hc * W2T + t] = w2[i];
    }
    __syncthreads();

    int gid = blockIdx.x * blockDim.x + threadIdx.x;
    int d = gid >> 2;
    if (d >= N) return;
    int q = gid & 3;
    int k0 = rowptr[d], k1 = rowptr[d + 1];

    float acc[NCLS];
    #pragma unroll
    for (int c = 0; c < NCLS; ++c) acc[c] = 0.f;

    for (int k = k0 + q; k < k1; k += 4) {
        int2 v = e2[k];
        int s = v.x & 0x1FFFF;
        int t = ((unsigned)v.x) >> 17;
        float inv = sinv[k];
        const float4* h4 = reinterpret_cast<const float4*>(h + (size_t)s * HID);
        float tmp[NCLS];
        #pragma unroll
        for (int c = 0; c < NCLS; ++c) tmp[c] = 0.f;
        #pragma unroll
        for (int p = 0; p < HID / 4; ++p) {
            float4 hv = h4[p];
            float hvv[4] = {hv.x, hv.y, hv.z, hv.w};
            #pragma unroll
            for (int j = 0; j < 4; ++j) {
                int i = 4 * p + j;
                #pragma unroll
                for (int c = 0; c < NCLS; ++c)
                    tmp[c] += hvv[j] * w2s[(i * NCLS + c) * W2T + t];
            }
        }
        #pragma unroll
        for (int c = 0; c < NCLS; ++c) acc[c] += inv * tmp[c];
    }

    #pragma unroll
    for (int c = 0; c < NCLS; ++c) {
        acc[c] += __shfl_xor(acc[c], 1);
        acc[c] += __shfl_xor(acc[c], 2);
    }

    if (q == 0) {
        const float4* h4 = reinterpret_cast<const float4*>(h + (size_t)d * HID);
        #pragma unroll
        for (int p = 0; p < HID / 4; ++p) {
            float4 hv = h4[p];
            float hvv[4] = {hv.x, hv.y, hv.z, hv.w};
            #pragma unroll
            for (int j = 0; j < 4; ++j) {
                int i = 4 * p + j;
                #pragma unroll
                for (int c = 0; c < NCLS; ++c)
                    acc[c] += hvv[j] * root2[i * NCLS + c];
            }
        }
        #pragma unroll
        for (int c = 0; c < NCLS; ++c) acc[c] += bias2[c];
        float4* o4 = reinterpret_cast<float4*>(out + (size_t)d * NCLS);
        o4[0] = make_float4(acc[0], acc[1], acc[2], acc[3]);
        o4[1] = make_float4(acc[4], acc[5], acc[6], acc[7]);
    }
}

// ---------------- launch ----------------

extern "C" void kernel_launch(void* const* d_in, const int* in_sizes, int n_in,
                              void* d_out, int out_size, void* d_ws, size_t ws_size,
                              hipStream_t stream) {
    const int*   edge_index = (const int*)  d_in[0];
    const int*   edge_type  = (const int*)  d_in[1];
    const float* basis1     = (const float*)d_in[2];
    const float* comp1      = (const float*)d_in[3];
    const float* root1      = (const float*)d_in[4];
    const float* bias1      = (const float*)d_in[5];
    const float* basis2     = (const float*)d_in[6];
    const float* comp2      = (const float*)d_in[7];
    const float* root2      = (const float*)d_in[8];
    const float* bias2      = (const float*)d_in[9];
    float* out = (float*)d_out;

    const int E = in_sizes[1];
    const int N = in_sizes[4] / HID;
    const int nbuk = (N + BWID - 1) >> SHIFT;
    const int* src = edge_index;
    const int* dst = edge_index + E;

    char* base = (char*)d_ws;
    size_t off = 0;
    auto alloc = [&](size_t bytes, size_t align) -> char* {
        off = (off + align - 1) & ~(align - 1);
        char* p = base + off;
        off += bytes;
        return p;
    };
    // contiguous zero region: hs | hd
    int*  hs     = (int*)  alloc((size_t)NBUKMAX * 4, 4);
    int*  hd     = (int*)  alloc((size_t)NBUKMAX * 4, 4);
    int*  gcs    = (int*)  alloc((size_t)NBUKMAX * 4, 4);
    int*  gcd    = (int*)  alloc((size_t)NBUKMAX * 4, 4);
    int*  based  = (int*)  alloc((size_t)(NBUKMAX + 1) * 4, 4);
    int*  rowptr = (int*)  alloc((size_t)(N + 1) * 4, 4);
    float* w2    = (float*)alloc((size_t)NREL * HID * NCLS * 4, 16);
    float* h     = (float*)alloc((size_t)N * HID * 4, 16);
    float* sinv  = (float*)alloc((size_t)E * 4, 4);
    int2* A      = (int2*) alloc((size_t)E * 8, 8);
    int2* B      = (int2*) alloc((size_t)E * 8, 8);
    int2* e2     = (int2*) alloc((size_t)E * 8, 8);
    float* msg   = (float*)alloc((size_t)E * HID * 4, 16);

    hipMemsetAsync(hs, 0, (size_t)NBUKMAX * 2 * 4, stream);

    {   int M = NREL * HID * NCLS;
        compute_w2_kernel<<<(M + 255) / 256, 256, 0, stream>>>(comp2, basis2, w2);
    }
    ghist_kernel<<<2048, 256, 0, stream>>>(src, dst, hs, hd, E, nbuk);
    scanbuk_kernel<<<1, 256, 0, stream>>>(hs, hd, gcs, based, gcd, nbuk, E);

    int nblk = (E + TILE - 1) / TILE;
    pass1_kernel<<<nblk, 256, 0, stream>>>(src, dst, edge_type, gcs, A, E);
    pass2_kernel<<<nblk, 256, 0, stream>>>(A, gcd, B, E);
    pass3_kernel<<<nbuk, 256, 0, stream>>>(B, based, e2, rowptr, N, E);

    {   long total = (long)E * 4;
        layer1A_kernel<<<(int)((total + 255) / 256), 256, 0, stream>>>(
            A, comp1, basis1, msg, E, N);
    }
    layer1B_kernel<<<(N + 255) / 256, 256, 0, stream>>>(
        e2, rowptr, msg, root1, bias1, h, sinv, N);
    {   long total = (long)N * 4;
        layer2_kernel<<<(int)((total + 255) / 256), 256, 0, stream>>>(
            e2, rowptr, sinv, w2, h, root2, bias2, out, N);
    }
}

// Round 7
// 631.601 us; speedup vs baseline: 2.6425x; 1.1473x over previous
//
#include <hip/hip_runtime.h>

#define NREL   50
#define NBASE  30
#define HID    16
#define NCLS   8

#define SHIFT   9
#define BWID    (1 << SHIFT)       // 512 nodes per bucket
#define NBUKMAX 512                // supports N <= 262144
#define TILE    4096               // edges per scatter block
#define EPB     16                 // edges per thread (256 threads)
#define W2T     56                 // padded t-stride for w2 LDS

typedef float vf4 __attribute__((ext_vector_type(4)));   // native vec for nontemporal builtins

// bijective chunked XCD swizzle (8 XCDs): each XCD gets a contiguous
// chunk of logical blocks -> src-bucket windows stay in ONE L2.
__device__ inline int xcd_swizzle(int orig, int nblk) {
    const int NX = 8;
    int xcd = orig % NX;
    int idx = orig / NX;
    int q = nblk / NX, r = nblk % NX;
    int base = (xcd < r) ? xcd * (q + 1) : r * (q + 1) + (xcd - r) * q;
    return base + idx;
}

// ---------------- setup ----------------

__global__ void compute_w2_kernel(const float* __restrict__ comp2,
                                  const float* __restrict__ basis2,
                                  float* __restrict__ w2) {
    int i = blockIdx.x * blockDim.x + threadIdx.x;
    if (i >= NREL * HID * NCLS) return;
    int r  = i / (HID * NCLS);
    int hc = i % (HID * NCLS);
    float acc = 0.f;
    #pragma unroll
    for (int b = 0; b < NBASE; ++b)
        acc += comp2[r * NBASE + b] * basis2[b * HID * NCLS + hc];
    w2[i] = acc;
}

// ---------------- bucket histograms (LDS-privatized) ----------------

__global__ void ghist_kernel(const int* __restrict__ src,
                             const int* __restrict__ dst,
                             int* __restrict__ hs, int* __restrict__ hd,
                             int E, int nbuk) {
    __shared__ int lhs[NBUKMAX], lhd[NBUKMAX];
    for (int j = threadIdx.x; j < nbuk; j += blockDim.x) { lhs[j] = 0; lhd[j] = 0; }
    __syncthreads();
    for (long e = (long)blockIdx.x * blockDim.x + threadIdx.x; e < E;
         e += (long)gridDim.x * blockDim.x) {
        atomicAdd(&lhs[src[e] >> SHIFT], 1);
        atomicAdd(&lhd[dst[e] >> SHIFT], 1);
    }
    __syncthreads();
    for (int j = threadIdx.x; j < nbuk; j += blockDim.x) {
        if (lhs[j]) atomicAdd(&hs[j], lhs[j]);
        if (lhd[j]) atomicAdd(&hd[j], lhd[j]);
    }
}

// exclusive scans of both histograms
__global__ void scanbuk_kernel(const int* __restrict__ hs, const int* __restrict__ hd,
                               int* __restrict__ gcs, int* __restrict__ based,
                               int* __restrict__ gcd, int nbuk, int E) {
    __shared__ int a[NBUKMAX], b[NBUKMAX];
    int tid = threadIdx.x;
    for (int j = tid; j < nbuk; j += blockDim.x) { a[j] = hs[j]; b[j] = hd[j]; }
    __syncthreads();
    if (tid == 0) {
        int run = 0;
        for (int i = 0; i < nbuk; ++i) { int v = a[i]; a[i] = run; run += v; }
        run = 0;
        for (int i = 0; i < nbuk; ++i) { int v = b[i]; b[i] = run; run += v; }
    }
    __syncthreads();
    for (int j = tid; j < nbuk; j += blockDim.x) {
        gcs[j] = a[j]; based[j] = b[j]; gcd[j] = b[j];
    }
    if (tid == 0) based[nbuk] = E;
}

// ---------------- pass 1: bucket-sort by src>>SHIFT ----------------
// Ax[pos] = s | t<<17 ; Ad[pos] = d
__global__ void pass1_kernel(const int* __restrict__ src,
                             const int* __restrict__ dst,
                             const int* __restrict__ et,
                             int* __restrict__ gcur,
                             int* __restrict__ Ax, int* __restrict__ Ad, int E) {
    __shared__ int lhist[NBUKMAX], lbase[NBUKMAX], lcur[NBUKMAX];
    int tid = threadIdx.x;
    for (int j = tid; j < NBUKMAX; j += 256) { lhist[j] = 0; lcur[j] = 0; }
    __syncthreads();
    int px[EPB], pd[EPB]; int bk[EPB];
    long e0 = (long)blockIdx.x * TILE;
    #pragma unroll
    for (int j = 0; j < EPB; ++j) {
        long e = e0 + j * 256 + tid;
        if (e < E) {
            int s = src[e], d = dst[e], t = et[e];
            px[j] = s | (t << 17);
            pd[j] = d;
            bk[j] = s >> SHIFT;
            atomicAdd(&lhist[bk[j]], 1);
        } else bk[j] = -1;
    }
    __syncthreads();
    for (int j = tid; j < NBUKMAX; j += 256)
        if (lhist[j] > 0) lbase[j] = atomicAdd(&gcur[j], lhist[j]);
    __syncthreads();
    #pragma unroll
    for (int j = 0; j < EPB; ++j) {
        if (bk[j] >= 0) {
            int r = atomicAdd(&lcur[bk[j]], 1);
            int pos = lbase[bk[j]] + r;
            Ax[pos] = px[j];
            Ad[pos] = pd[j];
        }
    }
}

// ---------------- pass 2: bucket-sort by dst>>SHIFT ----------------
// B[pos] = {s|t<<17, psi | dlow<<21}, psi = index into Ax (= msg row).
__global__ void pass2_kernel(const int* __restrict__ Ax,
                             const int* __restrict__ Ad,
                             int* __restrict__ gcur, int2* __restrict__ B, int E) {
    __shared__ int lhist[NBUKMAX], lbase[NBUKMAX], lcur[NBUKMAX];
    int tid = threadIdx.x;
    for (int j = tid; j < NBUKMAX; j += 256) { lhist[j] = 0; lcur[j] = 0; }
    __syncthreads();
    int2 p[EPB]; int bk[EPB];
    long e0 = (long)blockIdx.x * TILE;
    #pragma unroll
    for (int j = 0; j < EPB; ++j) {
        long e = e0 + j * 256 + tid;
        if (e < E) {
            int x = Ax[e];
            int d = Ad[e];
            p[j] = make_int2(x, (int)e | ((d & (BWID - 1)) << 21));
            bk[j] = d >> SHIFT;
            atomicAdd(&lhist[bk[j]], 1);
        } else bk[j] = -1;
    }
    __syncthreads();
    for (int j = tid; j < NBUKMAX; j += 256)
        if (lhist[j] > 0) lbase[j] = atomicAdd(&gcur[j], lhist[j]);
    __syncthreads();
    #pragma unroll
    for (int j = 0; j < EPB; ++j) {
        if (bk[j] >= 0) {
            int r = atomicAdd(&lcur[bk[j]], 1);
            B[lbase[bk[j]] + r] = p[j];
        }
    }
}

// ---------------- pass 3: exact dst grouping within each bucket ----------------
__global__ void pass3_kernel(const int2* __restrict__ B,
                             const int* __restrict__ based,
                             int2* __restrict__ e2, int* __restrict__ rowptr,
                             int N, int E) {
    __shared__ int lh[NBUKMAX], sA[NBUKMAX], sB[NBUKMAX];
    int blk = blockIdx.x, tid = threadIdx.x;
    int k0 = based[blk], k1 = based[blk + 1], cnt = k1 - k0;
    for (int j = tid; j < NBUKMAX; j += 256) lh[j] = 0;
    __syncthreads();
    for (int i = tid; i < cnt; i += 256) {
        int dlow = ((unsigned)B[k0 + i].y) >> 21;
        atomicAdd(&lh[dlow], 1);
    }
    __syncthreads();
    for (int j = tid; j < NBUKMAX; j += 256) sA[j] = lh[j];
    __syncthreads();
    int* cur = sA; int* oth = sB;
    for (int off = 1; off < NBUKMAX; off <<= 1) {
        for (int j = tid; j < NBUKMAX; j += 256)
            oth[j] = cur[j] + (j >= off ? cur[j - off] : 0);
        __syncthreads();
        int* t_ = cur; cur = oth; oth = t_;
    }
    for (int j = tid; j < NBUKMAX; j += 256) {
        int excl = cur[j] - lh[j];
        oth[j] = excl;
        int d = blk * BWID + j;
        if (d < N) rowptr[d] = k0 + excl;
    }
    __syncthreads();
    for (int i = tid; i < cnt; i += 256) {
        int2 b = B[k0 + i];
        int dlow = ((unsigned)b.y) >> 21;
        int pos = atomicAdd(&oth[dlow], 1);
        e2[k0 + pos] = make_int2(b.x, b.y & 0x1FFFFF);
    }
    if (blk == 0 && tid == 0) rowptr[N] = E;
}

// ---------------- layer 1 phase A (edge-centric, src-bucketed, XCD-chunked) ----------------
__global__ void layer1A_kernel(const int* __restrict__ Ax,
                               const float* __restrict__ comp1,
                               const float* __restrict__ basis1,
                               float* __restrict__ msg, int E, int N) {
    __shared__ float c1s[NREL * NBASE];
    for (int i = threadIdx.x; i < NREL * NBASE; i += blockDim.x)
        c1s[i] = comp1[i];
    __syncthreads();
    int blk = xcd_swizzle(blockIdx.x, gridDim.x);
    long idx = (long)blk * blockDim.x + threadIdx.x;
    long e = idx >> 2;
    if (e >= E) return;
    int q = (int)(idx & 3);
    int sx = Ax[e];
    int s = sx & 0x1FFFF;
    int t = ((unsigned)sx) >> 17;
    const float* cr = c1s + t * NBASE;
    const float* bp = basis1 + (long)s * HID + q * 4;
    long stride = (long)N * HID;
    float4 acc = make_float4(0.f, 0.f, 0.f, 0.f);
    #pragma unroll
    for (int b = 0; b < NBASE; ++b) {
        float4 x = *reinterpret_cast<const float4*>(bp + b * stride);
        float c = cr[b];
        acc.x += c * x.x; acc.y += c * x.y;
        acc.z += c * x.z; acc.w += c * x.w;
    }
    // msg is read exactly once later -> keep it out of L2 (don't evict basis windows)
    vf4 av = {acc.x, acc.y, acc.z, acc.w};
    __builtin_nontemporal_store(av, reinterpret_cast<vf4*>(msg + e * HID + q * 4));
}

// ---------------- layer 1 phase B ----------------
__global__ void layer1B_kernel(const int2* __restrict__ e2,
                               const int* __restrict__ rowptr,
                               const float* __restrict__ msg,
                               const float* __restrict__ root1,
                               const float* __restrict__ bias1,
                               float* __restrict__ h, float* __restrict__ sinv, int N) {
    int d = blockIdx.x * blockDim.x + threadIdx.x;
    if (d >= N) return;
    int k0 = rowptr[d], k1 = rowptr[d + 1];
    float acc[HID];
    #pragma unroll
    for (int i = 0; i < HID; ++i) acc[i] = 0.f;
    for (int k = k0; k < k1; ++k) {
        int2 v = e2[k];
        unsigned t = ((unsigned)v.x) >> 17;
        int c = 0;
        for (int j = k0; j < k1; ++j)
            c += ((((unsigned)e2[j].x) >> 17) == t);
        float inv = 1.0f / (float)c;
        sinv[k] = inv;
        const vf4* m4 = reinterpret_cast<const vf4*>(msg + (long)v.y * HID);
        #pragma unroll
        for (int p = 0; p < HID / 4; ++p) {
            vf4 m = __builtin_nontemporal_load(m4 + p);
            acc[4 * p + 0] += inv * m.x; acc[4 * p + 1] += inv * m.y;
            acc[4 * p + 2] += inv * m.z; acc[4 * p + 3] += inv * m.w;
        }
    }
    float4* h4 = reinterpret_cast<float4*>(h + (size_t)d * HID);
    #pragma unroll
    for (int p = 0; p < HID / 4; ++p) {
        float4 r = *reinterpret_cast<const float4*>(root1 + (size_t)d * HID + p * 4);
        float4 bv = *reinterpret_cast<const float4*>(bias1 + p * 4);
        h4[p] = make_float4(acc[4 * p + 0] + r.x + bv.x,
                            acc[4 * p + 1] + r.y + bv.y,
                            acc[4 * p + 2] + r.z + bv.z,
                            acc[4 * p + 3] + r.w + bv.w);
    }
}

// ---------------- layer 2 ----------------
__global__ void layer2_kernel(const int2* __restrict__ e2,
                              const int* __restrict__ rowptr,
                              const float* __restrict__ sinv,
                              const float* __restrict__ w2,
                              const float* __restrict__ h,
                              const float* __restrict__ root2,
                              const float* __restrict__ bias2,
                              float* __restrict__ out, int N) {
    __shared__ float w2s[HID * NCLS * W2T];
    for (int i = threadIdx.x; i < NREL * HID * NCLS; i += blockDim.x) {
        int t = i / (HID * NCLS);
        int hc = i % (HID * NCLS);
        w2s[hc * W2T + t] = w2[i];
    }
    __syncthreads();

    int gid = blockIdx.x * blockDim.x + threadIdx.x;
    int d = gid >> 2;
    if (d >= N) return;
    int q = gid & 3;
    int k0 = rowptr[d], k1 = rowptr[d + 1];

    float acc[NCLS];
    #pragma unroll
    for (int c = 0; c < NCLS; ++c) acc[c] = 0.f;

    for (int k = k0 + q; k < k1; k += 4) {
        int2 v = e2[k];
        int s = v.x & 0x1FFFF;
        int t = ((unsigned)v.x) >> 17;
        float inv = sinv[k];
        const float4* h4 = reinterpret_cast<const float4*>(h + (size_t)s * HID);
        float tmp[NCLS];
        #pragma unroll
        for (int c = 0; c < NCLS; ++c) tmp[c] = 0.f;
        #pragma unroll
        for (int p = 0; p < HID / 4; ++p) {
            float4 hv = h4[p];
            float hvv[4] = {hv.x, hv.y, hv.z, hv.w};
            #pragma unroll
            for (int j = 0; j < 4; ++j) {
                int i = 4 * p + j;
                #pragma unroll
                for (int c = 0; c < NCLS; ++c)
                    tmp[c] += hvv[j] * w2s[(i * NCLS + c) * W2T + t];
            }
        }
        #pragma unroll
        for (int c = 0; c < NCLS; ++c) acc[c] += inv * tmp[c];
    }

    #pragma unroll
    for (int c = 0; c < NCLS; ++c) {
        acc[c] += __shfl_xor(acc[c], 1);
        acc[c] += __shfl_xor(acc[c], 2);
    }

    if (q == 0) {
        const float4* h4 = reinterpret_cast<const float4*>(h + (size_t)d * HID);
        #pragma unroll
        for (int p = 0; p < HID / 4; ++p) {
            float4 hv = h4[p];
            float hvv[4] = {hv.x, hv.y, hv.z, hv.w};
            #pragma unroll
            for (int j = 0; j < 4; ++j) {
                int i = 4 * p + j;
                #pragma unroll
                for (int c = 0; c < NCLS; ++c)
                    acc[c] += hvv[j] * root2[i * NCLS + c];
            }
        }
        #pragma unroll
        for (int c = 0; c < NCLS; ++c) acc[c] += bias2[c];
        float4* o4 = reinterpret_cast<float4*>(out + (size_t)d * NCLS);
        o4[0] = make_float4(acc[0], acc[1], acc[2], acc[3]);
        o4[1] = make_float4(acc[4], acc[5], acc[6], acc[7]);
    }
}

// ---------------- launch ----------------

extern "C" void kernel_launch(void* const* d_in, const int* in_sizes, int n_in,
                              void* d_out, int out_size, void* d_ws, size_t ws_size,
                              hipStream_t stream) {
    const int*   edge_index = (const int*)  d_in[0];
    const int*   edge_type  = (const int*)  d_in[1];
    const float* basis1     = (const float*)d_in[2];
    const float* comp1      = (const float*)d_in[3];
    const float* root1      = (const float*)d_in[4];
    const float* bias1      = (const float*)d_in[5];
    const float* basis2     = (const float*)d_in[6];
    const float* comp2      = (const float*)d_in[7];
    const float* root2      = (const float*)d_in[8];
    const float* bias2      = (const float*)d_in[9];
    float* out = (float*)d_out;

    const int E = in_sizes[1];
    const int N = in_sizes[4] / HID;
    const int nbuk = (N + BWID - 1) >> SHIFT;
    const int* src = edge_index;
    const int* dst = edge_index + E;

    char* base = (char*)d_ws;
    size_t off = 0;
    auto alloc = [&](size_t bytes, size_t align) -> char* {
        off = (off + align - 1) & ~(align - 1);
        char* p = base + off;
        off += bytes;
        return p;
    };
    // contiguous zero region: hs | hd
    int*  hs     = (int*)  alloc((size_t)NBUKMAX * 4, 4);
    int*  hd     = (int*)  alloc((size_t)NBUKMAX * 4, 4);
    int*  gcs    = (int*)  alloc((size_t)NBUKMAX * 4, 4);
    int*  gcd    = (int*)  alloc((size_t)NBUKMAX * 4, 4);
    int*  based  = (int*)  alloc((size_t)(NBUKMAX + 1) * 4, 4);
    int*  rowptr = (int*)  alloc((size_t)(N + 1) * 4, 4);
    float* w2    = (float*)alloc((size_t)NREL * HID * NCLS * 4, 16);
    float* h     = (float*)alloc((size_t)N * HID * 4, 16);
    float* sinv  = (float*)alloc((size_t)E * 4, 4);
    int*  Ax     = (int*)  alloc((size_t)E * 4, 4);
    int*  Ad     = (int*)  alloc((size_t)E * 4, 4);
    int2* B      = (int2*) alloc((size_t)E * 8, 8);
    int2* e2     = (int2*) alloc((size_t)E * 8, 8);
    float* msg   = (float*)alloc((size_t)E * HID * 4, 16);

    hipMemsetAsync(hs, 0, (size_t)NBUKMAX * 2 * 4, stream);

    {   int M = NREL * HID * NCLS;
        compute_w2_kernel<<<(M + 255) / 256, 256, 0, stream>>>(comp2, basis2, w2);
    }
    ghist_kernel<<<2048, 256, 0, stream>>>(src, dst, hs, hd, E, nbuk);
    scanbuk_kernel<<<1, 256, 0, stream>>>(hs, hd, gcs, based, gcd, nbuk, E);

    int nblk = (E + TILE - 1) / TILE;
    pass1_kernel<<<nblk, 256, 0, stream>>>(src, dst, edge_type, gcs, Ax, Ad, E);
    pass2_kernel<<<nblk, 256, 0, stream>>>(Ax, Ad, gcd, B, E);
    pass3_kernel<<<nbuk, 256, 0, stream>>>(B, based, e2, rowptr, N, E);

    {   long total = (long)E * 4;
        layer1A_kernel<<<(int)((total + 255) / 256), 256, 0, stream>>>(
            Ax, comp1, basis1, msg, E, N);
    }
    layer1B_kernel<<<(N + 255) / 256, 256, 0, stream>>>(
        e2, rowptr, msg, root1, bias1, h, sinv, N);
    {   long total = (long)N * 4;
        layer2_kernel<<<(int)((total + 255) / 256), 256, 0, stream>>>(
            e2, rowptr, sinv, w2, h, root2, bias2, out, N);
    }
}

// Round 8
// 581.861 us; speedup vs baseline: 2.8684x; 1.0855x over previous
//
#include <hip/hip_runtime.h>

#define NREL   50
#define NBASE  30
#define HID    16
#define NCLS   8

#define SHIFT   9
#define BWID    (1 << SHIFT)       // 512 nodes per bucket
#define NBUKMAX 512                // supports N <= 262144
#define TILE    4096               // edges per scatter block
#define EPB     16                 // edges per thread (256 threads)
#define W2T     56                 // padded t-stride for w2 LDS

typedef float vf4 __attribute__((ext_vector_type(4)));

// ---------------- setup ----------------

__global__ void compute_w2_kernel(const float* __restrict__ comp2,
                                  const float* __restrict__ basis2,
                                  float* __restrict__ w2) {
    int i = blockIdx.x * blockDim.x + threadIdx.x;
    if (i >= NREL * HID * NCLS) return;
    int r  = i / (HID * NCLS);
    int hc = i % (HID * NCLS);
    float acc = 0.f;
    #pragma unroll
    for (int b = 0; b < NBASE; ++b)
        acc += comp2[r * NBASE + b] * basis2[b * HID * NCLS + hc];
    w2[i] = acc;
}

// ---------------- bucket histograms (LDS-privatized) ----------------

__global__ void ghist_kernel(const int* __restrict__ src,
                             const int* __restrict__ dst,
                             int* __restrict__ hs, int* __restrict__ hd,
                             int E, int nbuk) {
    __shared__ int lhs[NBUKMAX], lhd[NBUKMAX];
    for (int j = threadIdx.x; j < nbuk; j += blockDim.x) { lhs[j] = 0; lhd[j] = 0; }
    __syncthreads();
    for (long e = (long)blockIdx.x * blockDim.x + threadIdx.x; e < E;
         e += (long)gridDim.x * blockDim.x) {
        atomicAdd(&lhs[src[e] >> SHIFT], 1);
        atomicAdd(&lhd[dst[e] >> SHIFT], 1);
    }
    __syncthreads();
    for (int j = threadIdx.x; j < nbuk; j += blockDim.x) {
        if (lhs[j]) atomicAdd(&hs[j], lhs[j]);
        if (lhd[j]) atomicAdd(&hd[j], lhd[j]);
    }
}

// exclusive scans of both histograms; keeps pristine bases for pass1b/pass3
__global__ void scanbuk_kernel(const int* __restrict__ hs, const int* __restrict__ hd,
                               int* __restrict__ gcs, int* __restrict__ bases_s,
                               int* __restrict__ based, int* __restrict__ gcd,
                               int nbuk, int E) {
    __shared__ int a[NBUKMAX], b[NBUKMAX];
    int tid = threadIdx.x;
    for (int j = tid; j < nbuk; j += blockDim.x) { a[j] = hs[j]; b[j] = hd[j]; }
    __syncthreads();
    if (tid == 0) {
        int run = 0;
        for (int i = 0; i < nbuk; ++i) { int v = a[i]; a[i] = run; run += v; }
        run = 0;
        for (int i = 0; i < nbuk; ++i) { int v = b[i]; b[i] = run; run += v; }
    }
    __syncthreads();
    for (int j = tid; j < nbuk; j += blockDim.x) {
        gcs[j] = a[j]; bases_s[j] = a[j];
        based[j] = b[j]; gcd[j] = b[j];
    }
    if (tid == 0) { bases_s[nbuk] = E; based[nbuk] = E; }
}

// ---------------- pass 1: coarse bucket-sort by src>>SHIFT ----------------
__global__ void pass1_kernel(const int* __restrict__ src,
                             const int* __restrict__ dst,
                             const int* __restrict__ et,
                             int* __restrict__ gcur,
                             int* __restrict__ Ax0, int* __restrict__ Ad0, int E) {
    __shared__ int lhist[NBUKMAX], lbase[NBUKMAX], lcur[NBUKMAX];
    int tid = threadIdx.x;
    for (int j = tid; j < NBUKMAX; j += 256) { lhist[j] = 0; lcur[j] = 0; }
    __syncthreads();
    int px[EPB], pd[EPB]; int bk[EPB];
    long e0 = (long)blockIdx.x * TILE;
    #pragma unroll
    for (int j = 0; j < EPB; ++j) {
        long e = e0 + j * 256 + tid;
        if (e < E) {
            int s = src[e], d = dst[e], t = et[e];
            px[j] = s | (t << 17);
            pd[j] = d;
            bk[j] = s >> SHIFT;
            atomicAdd(&lhist[bk[j]], 1);
        } else bk[j] = -1;
    }
    __syncthreads();
    for (int j = tid; j < NBUKMAX; j += 256)
        if (lhist[j] > 0) lbase[j] = atomicAdd(&gcur[j], lhist[j]);
    __syncthreads();
    #pragma unroll
    for (int j = 0; j < EPB; ++j) {
        if (bk[j] >= 0) {
            int r = atomicAdd(&lcur[bk[j]], 1);
            int pos = lbase[bk[j]] + r;
            Ax0[pos] = px[j];
            Ad0[pos] = pd[j];
        }
    }
}

// ---------------- pass 1b: exact src grouping within each bucket ----------------
// outputs Ax/Ad in exact-src order + node-level rowptr_s
__global__ void pass1b_kernel(const int* __restrict__ Ax0,
                              const int* __restrict__ Ad0,
                              const int* __restrict__ bases_s,
                              int* __restrict__ Ax, int* __restrict__ Ad,
                              int* __restrict__ rowptr_s, int N, int E) {
    __shared__ int lh[BWID], sA[BWID], sB[BWID];
    int blk = blockIdx.x, tid = threadIdx.x;
    int k0 = bases_s[blk], k1 = bases_s[blk + 1], cnt = k1 - k0;
    for (int j = tid; j < BWID; j += 256) lh[j] = 0;
    __syncthreads();
    for (int i = tid; i < cnt; i += 256) {
        int slow = Ax0[k0 + i] & (BWID - 1);
        atomicAdd(&lh[slow], 1);
    }
    __syncthreads();
    for (int j = tid; j < BWID; j += 256) sA[j] = lh[j];
    __syncthreads();
    int* cur = sA; int* oth = sB;
    for (int off = 1; off < BWID; off <<= 1) {
        for (int j = tid; j < BWID; j += 256)
            oth[j] = cur[j] + (j >= off ? cur[j - off] : 0);
        __syncthreads();
        int* t_ = cur; cur = oth; oth = t_;
    }
    for (int j = tid; j < BWID; j += 256) {
        int excl = cur[j] - lh[j];
        oth[j] = excl;
        int s = blk * BWID + j;
        if (s < N) rowptr_s[s] = k0 + excl;
    }
    __syncthreads();
    for (int i = tid; i < cnt; i += 256) {
        int x = Ax0[k0 + i], d = Ad0[k0 + i];
        int slow = x & (BWID - 1);
        int pos = atomicAdd(&oth[slow], 1);
        Ax[k0 + pos] = x;
        Ad[k0 + pos] = d;
    }
    if (blk == 0 && tid == 0) rowptr_s[N] = E;
}

// ---------------- pass 2: bucket-sort by dst>>SHIFT ----------------
// B[pos] = {s|t<<17, psi | dlow<<21}, psi = index into Ax (= msg row).
__global__ void pass2_kernel(const int* __restrict__ Ax,
                             const int* __restrict__ Ad,
                             int* __restrict__ gcur, int2* __restrict__ B, int E) {
    __shared__ int lhist[NBUKMAX], lbase[NBUKMAX], lcur[NBUKMAX];
    int tid = threadIdx.x;
    for (int j = tid; j < NBUKMAX; j += 256) { lhist[j] = 0; lcur[j] = 0; }
    __syncthreads();
    int2 p[EPB]; int bk[EPB];
    long e0 = (long)blockIdx.x * TILE;
    #pragma unroll
    for (int j = 0; j < EPB; ++j) {
        long e = e0 + j * 256 + tid;
        if (e < E) {
            int x = Ax[e];
            int d = Ad[e];
            p[j] = make_int2(x, (int)e | ((d & (BWID - 1)) << 21));
            bk[j] = d >> SHIFT;
            atomicAdd(&lhist[bk[j]], 1);
        } else bk[j] = -1;
    }
    __syncthreads();
    for (int j = tid; j < NBUKMAX; j += 256)
        if (lhist[j] > 0) lbase[j] = atomicAdd(&gcur[j], lhist[j]);
    __syncthreads();
    #pragma unroll
    for (int j = 0; j < EPB; ++j) {
        if (bk[j] >= 0) {
            int r = atomicAdd(&lcur[bk[j]], 1);
            B[lbase[bk[j]] + r] = p[j];
        }
    }
}

// ---------------- pass 3: exact dst grouping within each bucket ----------------
__global__ void pass3_kernel(const int2* __restrict__ B,
                             const int* __restrict__ based,
                             int2* __restrict__ e2, int* __restrict__ rowptr,
                             int N, int E) {
    __shared__ int lh[BWID], sA[BWID], sB[BWID];
    int blk = blockIdx.x, tid = threadIdx.x;
    int k0 = based[blk], k1 = based[blk + 1], cnt = k1 - k0;
    for (int j = tid; j < BWID; j += 256) lh[j] = 0;
    __syncthreads();
    for (int i = tid; i < cnt; i += 256) {
        int dlow = ((unsigned)B[k0 + i].y) >> 21;
        atomicAdd(&lh[dlow], 1);
    }
    __syncthreads();
    for (int j = tid; j < BWID; j += 256) sA[j] = lh[j];
    __syncthreads();
    int* cur = sA; int* oth = sB;
    for (int off = 1; off < BWID; off <<= 1) {
        for (int j = tid; j < BWID; j += 256)
            oth[j] = cur[j] + (j >= off ? cur[j - off] : 0);
        __syncthreads();
        int* t_ = cur; cur = oth; oth = t_;
    }
    for (int j = tid; j < BWID; j += 256) {
        int excl = cur[j] - lh[j];
        oth[j] = excl;
        int d = blk * BWID + j;
        if (d < N) rowptr[d] = k0 + excl;
    }
    __syncthreads();
    for (int i = tid; i < cnt; i += 256) {
        int2 b = B[k0 + i];
        int dlow = ((unsigned)b.y) >> 21;
        int pos = atomicAdd(&oth[dlow], 1);
        e2[k0 + pos] = make_int2(b.x, b.y & 0x1FFFFF);
    }
    if (blk == 0 && tid == 0) rowptr[N] = E;
}

// ---------------- layer 1 phase A: NODE-CENTRIC ----------------
// 16 lanes per src node; lane = hidden channel. Basis rows for this src are
// loaded ONCE into 30 registers (sequential 64B lines), then every out-edge
// is computed from registers (comp1 broadcast from LDS). msg written at the
// edge's exact-src-order index (64B per edge, nontemporal).
__global__ void layer1A_node_kernel(const int* __restrict__ Ax,
                                    const int* __restrict__ rowptr_s,
                                    const float* __restrict__ comp1,
                                    const float* __restrict__ basis1,
                                    float* __restrict__ msg, int N) {
    __shared__ float c1s[NREL * NBASE];
    for (int i = threadIdx.x; i < NREL * NBASE; i += blockDim.x)
        c1s[i] = comp1[i];
    __syncthreads();
    int gid = threadIdx.x >> 4;
    int l   = threadIdx.x & 15;
    int s = blockIdx.x * 16 + gid;
    if (s >= N) return;
    int k0 = rowptr_s[s], k1 = rowptr_s[s + 1];
    if (k0 == k1) return;

    float breg[NBASE];
    long stride = (long)N * HID;
    const float* bp = basis1 + (long)s * HID + l;
    #pragma unroll
    for (int b = 0; b < NBASE; ++b)
        breg[b] = bp[b * stride];

    for (int k = k0; k < k1; ++k) {
        int t = ((unsigned)Ax[k]) >> 17;
        const float* cr = c1s + t * NBASE;
        float acc = 0.f;
        #pragma unroll
        for (int b = 0; b < NBASE; ++b)
            acc += cr[b] * breg[b];
        __builtin_nontemporal_store(acc, &msg[(long)k * HID + l]);
    }
}

// ---------------- layer 1 phase B ----------------
__global__ void layer1B_kernel(const int2* __restrict__ e2,
                               const int* __restrict__ rowptr,
                               const float* __restrict__ msg,
                               const float* __restrict__ root1,
                               const float* __restrict__ bias1,
                               float* __restrict__ h, float* __restrict__ sinv, int N) {
    int d = blockIdx.x * blockDim.x + threadIdx.x;
    if (d >= N) return;
    int k0 = rowptr[d], k1 = rowptr[d + 1];
    float acc[HID];
    #pragma unroll
    for (int i = 0; i < HID; ++i) acc[i] = 0.f;
    for (int k = k0; k < k1; ++k) {
        int2 v = e2[k];
        unsigned t = ((unsigned)v.x) >> 17;
        int c = 0;
        for (int j = k0; j < k1; ++j)
            c += ((((unsigned)e2[j].x) >> 17) == t);
        float inv = 1.0f / (float)c;
        sinv[k] = inv;
        const vf4* m4 = reinterpret_cast<const vf4*>(msg + (long)v.y * HID);
        #pragma unroll
        for (int p = 0; p < HID / 4; ++p) {
            vf4 m = __builtin_nontemporal_load(m4 + p);
            acc[4 * p + 0] += inv * m.x; acc[4 * p + 1] += inv * m.y;
            acc[4 * p + 2] += inv * m.z; acc[4 * p + 3] += inv * m.w;
        }
    }
    float4* h4 = reinterpret_cast<float4*>(h + (size_t)d * HID);
    #pragma unroll
    for (int p = 0; p < HID / 4; ++p) {
        float4 r = *reinterpret_cast<const float4*>(root1 + (size_t)d * HID + p * 4);
        float4 bv = *reinterpret_cast<const float4*>(bias1 + p * 4);
        h4[p] = make_float4(acc[4 * p + 0] + r.x + bv.x,
                            acc[4 * p + 1] + r.y + bv.y,
                            acc[4 * p + 2] + r.z + bv.z,
                            acc[4 * p + 3] + r.w + bv.w);
    }
}

// ---------------- layer 2 ----------------
__global__ void layer2_kernel(const int2* __restrict__ e2,
                              const int* __restrict__ rowptr,
                              const float* __restrict__ sinv,
                              const float* __restrict__ w2,
                              const float* __restrict__ h,
                              const float* __restrict__ root2,
                              const float* __restrict__ bias2,
                              float* __restrict__ out, int N) {
    __shared__ float w2s[HID * NCLS * W2T];
    for (int i = threadIdx.x; i < NREL * HID * NCLS; i += blockDim.x) {
        int t = i / (HID * NCLS);
        int hc = i % (HID * NCLS);
        w2s[hc * W2T + t] = w2[i];
    }
    __syncthreads();

    int gid = blockIdx.x * blockDim.x + threadIdx.x;
    int d = gid >> 2;
    if (d >= N) return;
    int q = gid & 3;
    int k0 = rowptr[d], k1 = rowptr[d + 1];

    float acc[NCLS];
    #pragma unroll
    for (int c = 0; c < NCLS; ++c) acc[c] = 0.f;

    for (int k = k0 + q; k < k1; k += 4) {
        int2 v = e2[k];
        int s = v.x & 0x1FFFF;
        int t = ((unsigned)v.x) >> 17;
        float inv = sinv[k];
        const float4* h4 = reinterpret_cast<const float4*>(h + (size_t)s * HID);
        float tmp[NCLS];
        #pragma unroll
        for (int c = 0; c < NCLS; ++c) tmp[c] = 0.f;
        #pragma unroll
        for (int p = 0; p < HID / 4; ++p) {
            float4 hv = h4[p];
            float hvv[4] = {hv.x, hv.y, hv.z, hv.w};
            #pragma unroll
            for (int j = 0; j < 4; ++j) {
                int i = 4 * p + j;
                #pragma unroll
                for (int c = 0; c < NCLS; ++c)
                    tmp[c] += hvv[j] * w2s[(i * NCLS + c) * W2T + t];
            }
        }
        #pragma unroll
        for (int c = 0; c < NCLS; ++c) acc[c] += inv * tmp[c];
    }

    #pragma unroll
    for (int c = 0; c < NCLS; ++c) {
        acc[c] += __shfl_xor(acc[c], 1);
        acc[c] += __shfl_xor(acc[c], 2);
    }

    if (q == 0) {
        const float4* h4 = reinterpret_cast<const float4*>(h + (size_t)d * HID);
        #pragma unroll
        for (int p = 0; p < HID / 4; ++p) {
            float4 hv = h4[p];
            float hvv[4] = {hv.x, hv.y, hv.z, hv.w};
            #pragma unroll
            for (int j = 0; j < 4; ++j) {
                int i = 4 * p + j;
                #pragma unroll
                for (int c = 0; c < NCLS; ++c)
                    acc[c] += hvv[j] * root2[i * NCLS + c];
            }
        }
        #pragma unroll
        for (int c = 0; c < NCLS; ++c) acc[c] += bias2[c];
        float4* o4 = reinterpret_cast<float4*>(out + (size_t)d * NCLS);
        o4[0] = make_float4(acc[0], acc[1], acc[2], acc[3]);
        o4[1] = make_float4(acc[4], acc[5], acc[6], acc[7]);
    }
}

// ---------------- launch ----------------

extern "C" void kernel_launch(void* const* d_in, const int* in_sizes, int n_in,
                              void* d_out, int out_size, void* d_ws, size_t ws_size,
                              hipStream_t stream) {
    const int*   edge_index = (const int*)  d_in[0];
    const int*   edge_type  = (const int*)  d_in[1];
    const float* basis1     = (const float*)d_in[2];
    const float* comp1      = (const float*)d_in[3];
    const float* root1      = (const float*)d_in[4];
    const float* bias1      = (const float*)d_in[5];
    const float* basis2     = (const float*)d_in[6];
    const float* comp2      = (const float*)d_in[7];
    const float* root2      = (const float*)d_in[8];
    const float* bias2      = (const float*)d_in[9];
    float* out = (float*)d_out;

    const int E = in_sizes[1];
    const int N = in_sizes[4] / HID;
    const int nbuk = (N + BWID - 1) >> SHIFT;
    const int* src = edge_index;
    const int* dst = edge_index + E;

    char* base = (char*)d_ws;
    size_t off = 0;
    auto alloc = [&](size_t bytes, size_t align) -> char* {
        off = (off + align - 1) & ~(align - 1);
        char* p = base + off;
        off += bytes;
        return p;
    };
    // contiguous zero region: hs | hd
    int*  hs       = (int*)  alloc((size_t)NBUKMAX * 4, 4);
    int*  hd       = (int*)  alloc((size_t)NBUKMAX * 4, 4);
    int*  gcs      = (int*)  alloc((size_t)NBUKMAX * 4, 4);
    int*  gcd      = (int*)  alloc((size_t)NBUKMAX * 4, 4);
    int*  bases_s  = (int*)  alloc((size_t)(NBUKMAX + 1) * 4, 4);
    int*  based    = (int*)  alloc((size_t)(NBUKMAX + 1) * 4, 4);
    int*  rowptr   = (int*)  alloc((size_t)(N + 1) * 4, 4);
    int*  rowptr_s = (int*)  alloc((size_t)(N + 1) * 4, 4);
    float* w2      = (float*)alloc((size_t)NREL * HID * NCLS * 4, 16);
    float* h       = (float*)alloc((size_t)N * HID * 4, 16);
    float* sinv    = (float*)alloc((size_t)E * 4, 4);
    int*  Ax0      = (int*)  alloc((size_t)E * 4, 4);
    int*  Ad0      = (int*)  alloc((size_t)E * 4, 4);
    int*  Ax       = (int*)  alloc((size_t)E * 4, 4);
    int*  Ad       = (int*)  alloc((size_t)E * 4, 4);
    int2* B        = (int2*) alloc((size_t)E * 8, 8);
    int2* e2       = (int2*) alloc((size_t)E * 8, 8);
    float* msg     = (float*)alloc((size_t)E * HID * 4, 16);

    hipMemsetAsync(hs, 0, (size_t)NBUKMAX * 2 * 4, stream);

    {   int M = NREL * HID * NCLS;
        compute_w2_kernel<<<(M + 255) / 256, 256, 0, stream>>>(comp2, basis2, w2);
    }
    ghist_kernel<<<2048, 256, 0, stream>>>(src, dst, hs, hd, E, nbuk);
    scanbuk_kernel<<<1, 256, 0, stream>>>(hs, hd, gcs, bases_s, based, gcd, nbuk, E);

    int nblk = (E + TILE - 1) / TILE;
    pass1_kernel<<<nblk, 256, 0, stream>>>(src, dst, edge_type, gcs, Ax0, Ad0, E);
    pass1b_kernel<<<nbuk, 256, 0, stream>>>(Ax0, Ad0, bases_s, Ax, Ad, rowptr_s, N, E);
    pass2_kernel<<<nblk, 256, 0, stream>>>(Ax, Ad, gcd, B, E);
    pass3_kernel<<<nbuk, 256, 0, stream>>>(B, based, e2, rowptr, N, E);

    {   int blocks = (N + 15) / 16;
        layer1A_node_kernel<<<blocks, 256, 0, stream>>>(
            Ax, rowptr_s, comp1, basis1, msg, N);
    }
    layer1B_kernel<<<(N + 255) / 256, 256, 0, stream>>>(
        e2, rowptr, msg, root1, bias1, h, sinv, N);
    {   long total = (long)N * 4;
        layer2_kernel<<<(int)((total + 255) / 256), 256, 0, stream>>>(
            e2, rowptr, sinv, w2, h, root2, bias2, out, N);
    }
}

// Round 9
// 462.110 us; speedup vs baseline: 3.6118x; 1.2591x over previous
//
#include <hip/hip_runtime.h>

#define NREL   50
#define NBASE  30
#define HID    16
#define NCLS   8

#define SHIFT   9
#define BWID    (1 << SHIFT)       // 512 nodes per bucket
#define NBUKMAX 512                // supports N <= 262144
#define TILE    4096               // edges per scatter block
#define EPB     16                 // edges per thread (256 threads)
#define W2T     56                 // padded t-stride for w2 LDS

typedef float vf4 __attribute__((ext_vector_type(4)));

// ---------------- setup ----------------

__global__ void compute_w2_kernel(const float* __restrict__ comp2,
                                  const float* __restrict__ basis2,
                                  float* __restrict__ w2) {
    int i = blockIdx.x * blockDim.x + threadIdx.x;
    if (i >= NREL * HID * NCLS) return;
    int r  = i / (HID * NCLS);
    int hc = i % (HID * NCLS);
    float acc = 0.f;
    #pragma unroll
    for (int b = 0; b < NBASE; ++b)
        acc += comp2[r * NBASE + b] * basis2[b * HID * NCLS + hc];
    w2[i] = acc;
}

// ---------------- bucket histograms (LDS-privatized) ----------------

__global__ void ghist_kernel(const int* __restrict__ src,
                             const int* __restrict__ dst,
                             int* __restrict__ hs, int* __restrict__ hd,
                             int E, int nbuk) {
    __shared__ int lhs[NBUKMAX], lhd[NBUKMAX];
    for (int j = threadIdx.x; j < nbuk; j += blockDim.x) { lhs[j] = 0; lhd[j] = 0; }
    __syncthreads();
    for (long e = (long)blockIdx.x * blockDim.x + threadIdx.x; e < E;
         e += (long)gridDim.x * blockDim.x) {
        atomicAdd(&lhs[src[e] >> SHIFT], 1);
        atomicAdd(&lhd[dst[e] >> SHIFT], 1);
    }
    __syncthreads();
    for (int j = threadIdx.x; j < nbuk; j += blockDim.x) {
        if (lhs[j]) atomicAdd(&hs[j], lhs[j]);
        if (lhd[j]) atomicAdd(&hd[j], lhd[j]);
    }
}

// exclusive scans of both histograms; keeps pristine bases for pass1b/pass3
__global__ void scanbuk_kernel(const int* __restrict__ hs, const int* __restrict__ hd,
                               int* __restrict__ gcs, int* __restrict__ bases_s,
                               int* __restrict__ based, int* __restrict__ gcd,
                               int nbuk, int E) {
    __shared__ int a[NBUKMAX], b[NBUKMAX];
    int tid = threadIdx.x;
    for (int j = tid; j < nbuk; j += blockDim.x) { a[j] = hs[j]; b[j] = hd[j]; }
    __syncthreads();
    if (tid == 0) {
        int run = 0;
        for (int i = 0; i < nbuk; ++i) { int v = a[i]; a[i] = run; run += v; }
        run = 0;
        for (int i = 0; i < nbuk; ++i) { int v = b[i]; b[i] = run; run += v; }
    }
    __syncthreads();
    for (int j = tid; j < nbuk; j += blockDim.x) {
        gcs[j] = a[j]; bases_s[j] = a[j];
        based[j] = b[j]; gcd[j] = b[j];
    }
    if (tid == 0) { bases_s[nbuk] = E; based[nbuk] = E; }
}

// ---------------- pass 1: coarse bucket-sort by src>>SHIFT ----------------
__global__ void pass1_kernel(const int* __restrict__ src,
                             const int* __restrict__ dst,
                             const int* __restrict__ et,
                             int* __restrict__ gcur,
                             int* __restrict__ Ax0, int* __restrict__ Ad0, int E) {
    __shared__ int lhist[NBUKMAX], lbase[NBUKMAX], lcur[NBUKMAX];
    int tid = threadIdx.x;
    for (int j = tid; j < NBUKMAX; j += 256) { lhist[j] = 0; lcur[j] = 0; }
    __syncthreads();
    int px[EPB], pd[EPB]; int bk[EPB];
    long e0 = (long)blockIdx.x * TILE;
    #pragma unroll
    for (int j = 0; j < EPB; ++j) {
        long e = e0 + j * 256 + tid;
        if (e < E) {
            int s = src[e], d = dst[e], t = et[e];
            px[j] = s | (t << 17);
            pd[j] = d;
            bk[j] = s >> SHIFT;
            atomicAdd(&lhist[bk[j]], 1);
        } else bk[j] = -1;
    }
    __syncthreads();
    for (int j = tid; j < NBUKMAX; j += 256)
        if (lhist[j] > 0) lbase[j] = atomicAdd(&gcur[j], lhist[j]);
    __syncthreads();
    #pragma unroll
    for (int j = 0; j < EPB; ++j) {
        if (bk[j] >= 0) {
            int r = atomicAdd(&lcur[bk[j]], 1);
            int pos = lbase[bk[j]] + r;
            Ax0[pos] = px[j];
            Ad0[pos] = pd[j];
        }
    }
}

// ---------------- pass 1b: exact src grouping within each bucket ----------------
__global__ void pass1b_kernel(const int* __restrict__ Ax0,
                              const int* __restrict__ Ad0,
                              const int* __restrict__ bases_s,
                              int* __restrict__ Ax, int* __restrict__ Ad,
                              int* __restrict__ rowptr_s, int N, int E) {
    __shared__ int lh[BWID], sA[BWID], sB[BWID];
    int blk = blockIdx.x, tid = threadIdx.x;
    int k0 = bases_s[blk], k1 = bases_s[blk + 1], cnt = k1 - k0;
    for (int j = tid; j < BWID; j += 256) lh[j] = 0;
    __syncthreads();
    for (int i = tid; i < cnt; i += 256) {
        int slow = Ax0[k0 + i] & (BWID - 1);
        atomicAdd(&lh[slow], 1);
    }
    __syncthreads();
    for (int j = tid; j < BWID; j += 256) sA[j] = lh[j];
    __syncthreads();
    int* cur = sA; int* oth = sB;
    for (int off = 1; off < BWID; off <<= 1) {
        for (int j = tid; j < BWID; j += 256)
            oth[j] = cur[j] + (j >= off ? cur[j - off] : 0);
        __syncthreads();
        int* t_ = cur; cur = oth; oth = t_;
    }
    for (int j = tid; j < BWID; j += 256) {
        int excl = cur[j] - lh[j];
        oth[j] = excl;
        int s = blk * BWID + j;
        if (s < N) rowptr_s[s] = k0 + excl;
    }
    __syncthreads();
    for (int i = tid; i < cnt; i += 256) {
        int x = Ax0[k0 + i], d = Ad0[k0 + i];
        int slow = x & (BWID - 1);
        int pos = atomicAdd(&oth[slow], 1);
        Ax[k0 + pos] = x;
        Ad[k0 + pos] = d;
    }
    if (blk == 0 && tid == 0) rowptr_s[N] = E;
}

// ---------------- pass 2: bucket-sort by dst>>SHIFT ----------------
__global__ void pass2_kernel(const int* __restrict__ Ax,
                             const int* __restrict__ Ad,
                             int* __restrict__ gcur, int2* __restrict__ B, int E) {
    __shared__ int lhist[NBUKMAX], lbase[NBUKMAX], lcur[NBUKMAX];
    int tid = threadIdx.x;
    for (int j = tid; j < NBUKMAX; j += 256) { lhist[j] = 0; lcur[j] = 0; }
    __syncthreads();
    int2 p[EPB]; int bk[EPB];
    long e0 = (long)blockIdx.x * TILE;
    #pragma unroll
    for (int j = 0; j < EPB; ++j) {
        long e = e0 + j * 256 + tid;
        if (e < E) {
            int x = Ax[e];
            int d = Ad[e];
            p[j] = make_int2(x, (int)e | ((d & (BWID - 1)) << 21));
            bk[j] = d >> SHIFT;
            atomicAdd(&lhist[bk[j]], 1);
        } else bk[j] = -1;
    }
    __syncthreads();
    for (int j = tid; j < NBUKMAX; j += 256)
        if (lhist[j] > 0) lbase[j] = atomicAdd(&gcur[j], lhist[j]);
    __syncthreads();
    #pragma unroll
    for (int j = 0; j < EPB; ++j) {
        if (bk[j] >= 0) {
            int r = atomicAdd(&lcur[bk[j]], 1);
            B[lbase[bk[j]] + r] = p[j];
        }
    }
}

// ---------------- pass 3: exact dst grouping within each bucket ----------------
__global__ void pass3_kernel(const int2* __restrict__ B,
                             const int* __restrict__ based,
                             int2* __restrict__ e2, int* __restrict__ rowptr,
                             int N, int E) {
    __shared__ int lh[BWID], sA[BWID], sB[BWID];
    int blk = blockIdx.x, tid = threadIdx.x;
    int k0 = based[blk], k1 = based[blk + 1], cnt = k1 - k0;
    for (int j = tid; j < BWID; j += 256) lh[j] = 0;
    __syncthreads();
    for (int i = tid; i < cnt; i += 256) {
        int dlow = ((unsigned)B[k0 + i].y) >> 21;
        atomicAdd(&lh[dlow], 1);
    }
    __syncthreads();
    for (int j = tid; j < BWID; j += 256) sA[j] = lh[j];
    __syncthreads();
    int* cur = sA; int* oth = sB;
    for (int off = 1; off < BWID; off <<= 1) {
        for (int j = tid; j < BWID; j += 256)
            oth[j] = cur[j] + (j >= off ? cur[j - off] : 0);
        __syncthreads();
        int* t_ = cur; cur = oth; oth = t_;
    }
    for (int j = tid; j < BWID; j += 256) {
        int excl = cur[j] - lh[j];
        oth[j] = excl;
        int d = blk * BWID + j;
        if (d < N) rowptr[d] = k0 + excl;
    }
    __syncthreads();
    for (int i = tid; i < cnt; i += 256) {
        int2 b = B[k0 + i];
        int dlow = ((unsigned)b.y) >> 21;
        int pos = atomicAdd(&oth[dlow], 1);
        e2[k0 + pos] = make_int2(b.x, b.y & 0x1FFFFF);
    }
    if (blk == 0 && tid == 0) rowptr[N] = E;
}

// ---------------- layer 1 phase A: node-centric ----------------
__global__ void layer1A_node_kernel(const int* __restrict__ Ax,
                                    const int* __restrict__ rowptr_s,
                                    const float* __restrict__ comp1,
                                    const float* __restrict__ basis1,
                                    float* __restrict__ msg, int N) {
    __shared__ float c1s[NREL * NBASE];
    for (int i = threadIdx.x; i < NREL * NBASE; i += blockDim.x)
        c1s[i] = comp1[i];
    __syncthreads();
    int gid = threadIdx.x >> 4;
    int l   = threadIdx.x & 15;
    int s = blockIdx.x * 16 + gid;
    if (s >= N) return;
    int k0 = rowptr_s[s], k1 = rowptr_s[s + 1];
    if (k0 == k1) return;

    float breg[NBASE];
    long stride = (long)N * HID;
    const float* bp = basis1 + (long)s * HID + l;
    #pragma unroll
    for (int b = 0; b < NBASE; ++b)
        breg[b] = bp[b * stride];

    for (int k = k0; k < k1; ++k) {
        int t = ((unsigned)Ax[k]) >> 17;
        const float* cr = c1s + t * NBASE;
        float acc = 0.f;
        #pragma unroll
        for (int b = 0; b < NBASE; ++b)
            acc += cr[b] * breg[b];
        __builtin_nontemporal_store(acc, &msg[(long)k * HID + l]);
    }
}

// ---------------- layer 1 phase B: 8 threads per dst node (k-split) ----------------
__global__ void layer1B_kernel(const int2* __restrict__ e2,
                               const int* __restrict__ rowptr,
                               const float* __restrict__ msg,
                               const float* __restrict__ root1,
                               const float* __restrict__ bias1,
                               float* __restrict__ h, float* __restrict__ sinv, int N) {
    long gid = (long)blockIdx.x * blockDim.x + threadIdx.x;
    int d = (int)(gid >> 3);
    if (d >= N) return;
    int q = (int)(gid & 7);
    int k0 = rowptr[d], k1 = rowptr[d + 1];

    float acc[HID];
    #pragma unroll
    for (int i = 0; i < HID; ++i) acc[i] = 0.f;

    for (int k = k0 + q; k < k1; k += 8) {
        int2 v = e2[k];
        unsigned t = ((unsigned)v.x) >> 17;
        int c = 0;
        for (int j = k0; j < k1; ++j)
            c += ((((unsigned)e2[j].x) >> 17) == t);
        float inv = 1.0f / (float)c;
        sinv[k] = inv;
        const vf4* m4 = reinterpret_cast<const vf4*>(msg + (long)v.y * HID);
        #pragma unroll
        for (int p = 0; p < HID / 4; ++p) {
            vf4 m = __builtin_nontemporal_load(m4 + p);
            acc[4 * p + 0] += inv * m.x; acc[4 * p + 1] += inv * m.y;
            acc[4 * p + 2] += inv * m.z; acc[4 * p + 3] += inv * m.w;
        }
    }

    // reduce across the 8 lanes of this node
    #pragma unroll
    for (int i = 0; i < HID; ++i) {
        acc[i] += __shfl_xor(acc[i], 1);
        acc[i] += __shfl_xor(acc[i], 2);
        acc[i] += __shfl_xor(acc[i], 4);
    }

    if (q == 0) {
        float4* h4 = reinterpret_cast<float4*>(h + (size_t)d * HID);
        #pragma unroll
        for (int p = 0; p < HID / 4; ++p) {
            float4 r = *reinterpret_cast<const float4*>(root1 + (size_t)d * HID + p * 4);
            float4 bv = *reinterpret_cast<const float4*>(bias1 + p * 4);
            h4[p] = make_float4(acc[4 * p + 0] + r.x + bv.x,
                                acc[4 * p + 1] + r.y + bv.y,
                                acc[4 * p + 2] + r.z + bv.z,
                                acc[4 * p + 3] + r.w + bv.w);
        }
    }
}

// ---------------- layer 2 ----------------
__global__ void layer2_kernel(const int2* __restrict__ e2,
                              const int* __restrict__ rowptr,
                              const float* __restrict__ sinv,
                              const float* __restrict__ w2,
                              const float* __restrict__ h,
                              const float* __restrict__ root2,
                              const float* __restrict__ bias2,
                              float* __restrict__ out, int N) {
    __shared__ float w2s[HID * NCLS * W2T];
    for (int i = threadIdx.x; i < NREL * HID * NCLS; i += blockDim.x) {
        int t = i / (HID * NCLS);
        int hc = i % (HID * NCLS);
        w2s[hc * W2T + t] = w2[i];
    }
    __syncthreads();

    int gid = blockIdx.x * blockDim.x + threadIdx.x;
    int d = gid >> 2;
    if (d >= N) return;
    int q = gid & 3;
    int k0 = rowptr[d], k1 = rowptr[d + 1];

    float acc[NCLS];
    #pragma unroll
    for (int c = 0; c < NCLS; ++c) acc[c] = 0.f;

    for (int k = k0 + q; k < k1; k += 4) {
        int2 v = e2[k];
        int s = v.x & 0x1FFFF;
        int t = ((unsigned)v.x) >> 17;
        float inv = sinv[k];
        const float4* h4 = reinterpret_cast<const float4*>(h + (size_t)s * HID);
        float tmp[NCLS];
        #pragma unroll
        for (int c = 0; c < NCLS; ++c) tmp[c] = 0.f;
        #pragma unroll
        for (int p = 0; p < HID / 4; ++p) {
            float4 hv = h4[p];
            float hvv[4] = {hv.x, hv.y, hv.z, hv.w};
            #pragma unroll
            for (int j = 0; j < 4; ++j) {
                int i = 4 * p + j;
                #pragma unroll
                for (int c = 0; c < NCLS; ++c)
                    tmp[c] += hvv[j] * w2s[(i * NCLS + c) * W2T + t];
            }
        }
        #pragma unroll
        for (int c = 0; c < NCLS; ++c) acc[c] += inv * tmp[c];
    }

    #pragma unroll
    for (int c = 0; c < NCLS; ++c) {
        acc[c] += __shfl_xor(acc[c], 1);
        acc[c] += __shfl_xor(acc[c], 2);
    }

    if (q == 0) {
        const float4* h4 = reinterpret_cast<const float4*>(h + (size_t)d * HID);
        #pragma unroll
        for (int p = 0; p < HID / 4; ++p) {
            float4 hv = h4[p];
            float hvv[4] = {hv.x, hv.y, hv.z, hv.w};
            #pragma unroll
            for (int j = 0; j < 4; ++j) {
                int i = 4 * p + j;
                #pragma unroll
                for (int c = 0; c < NCLS; ++c)
                    acc[c] += hvv[j] * root2[i * NCLS + c];
            }
        }
        #pragma unroll
        for (int c = 0; c < NCLS; ++c) acc[c] += bias2[c];
        float4* o4 = reinterpret_cast<float4*>(out + (size_t)d * NCLS);
        o4[0] = make_float4(acc[0], acc[1], acc[2], acc[3]);
        o4[1] = make_float4(acc[4], acc[5], acc[6], acc[7]);
    }
}

// ---------------- launch ----------------

extern "C" void kernel_launch(void* const* d_in, const int* in_sizes, int n_in,
                              void* d_out, int out_size, void* d_ws, size_t ws_size,
                              hipStream_t stream) {
    const int*   edge_index = (const int*)  d_in[0];
    const int*   edge_type  = (const int*)  d_in[1];
    const float* basis1     = (const float*)d_in[2];
    const float* comp1      = (const float*)d_in[3];
    const float* root1      = (const float*)d_in[4];
    const float* bias1      = (const float*)d_in[5];
    const float* basis2     = (const float*)d_in[6];
    const float* comp2      = (const float*)d_in[7];
    const float* root2      = (const float*)d_in[8];
    const float* bias2      = (const float*)d_in[9];
    float* out = (float*)d_out;

    const int E = in_sizes[1];
    const int N = in_sizes[4] / HID;
    const int nbuk = (N + BWID - 1) >> SHIFT;
    const int* src = edge_index;
    const int* dst = edge_index + E;

    char* base = (char*)d_ws;
    size_t off = 0;
    auto alloc = [&](size_t bytes, size_t align) -> char* {
        off = (off + align - 1) & ~(align - 1);
        char* p = base + off;
        off += bytes;
        return p;
    };
    // contiguous zero region: hs | hd
    int*  hs       = (int*)  alloc((size_t)NBUKMAX * 4, 4);
    int*  hd       = (int*)  alloc((size_t)NBUKMAX * 4, 4);
    int*  gcs      = (int*)  alloc((size_t)NBUKMAX * 4, 4);
    int*  gcd      = (int*)  alloc((size_t)NBUKMAX * 4, 4);
    int*  bases_s  = (int*)  alloc((size_t)(NBUKMAX + 1) * 4, 4);
    int*  based    = (int*)  alloc((size_t)(NBUKMAX + 1) * 4, 4);
    int*  rowptr   = (int*)  alloc((size_t)(N + 1) * 4, 4);
    int*  rowptr_s = (int*)  alloc((size_t)(N + 1) * 4, 4);
    float* w2      = (float*)alloc((size_t)NREL * HID * NCLS * 4, 16);
    float* h       = (float*)alloc((size_t)N * HID * 4, 16);
    float* sinv    = (float*)alloc((size_t)E * 4, 4);
    int*  Ax0      = (int*)  alloc((size_t)E * 4, 4);
    int*  Ad0      = (int*)  alloc((size_t)E * 4, 4);
    int*  Ax       = (int*)  alloc((size_t)E * 4, 4);
    int*  Ad       = (int*)  alloc((size_t)E * 4, 4);
    int2* B        = (int2*) alloc((size_t)E * 8, 8);
    int2* e2       = (int2*) alloc((size_t)E * 8, 8);
    float* msg     = (float*)alloc((size_t)E * HID * 4, 16);

    hipMemsetAsync(hs, 0, (size_t)NBUKMAX * 2 * 4, stream);

    {   int M = NREL * HID * NCLS;
        compute_w2_kernel<<<(M + 255) / 256, 256, 0, stream>>>(comp2, basis2, w2);
    }
    ghist_kernel<<<2048, 256, 0, stream>>>(src, dst, hs, hd, E, nbuk);
    scanbuk_kernel<<<1, 256, 0, stream>>>(hs, hd, gcs, bases_s, based, gcd, nbuk, E);

    int nblk = (E + TILE - 1) / TILE;
    pass1_kernel<<<nblk, 256, 0, stream>>>(src, dst, edge_type, gcs, Ax0, Ad0, E);
    pass1b_kernel<<<nbuk, 256, 0, stream>>>(Ax0, Ad0, bases_s, Ax, Ad, rowptr_s, N, E);
    pass2_kernel<<<nblk, 256, 0, stream>>>(Ax, Ad, gcd, B, E);
    pass3_kernel<<<nbuk, 256, 0, stream>>>(B, based, e2, rowptr, N, E);

    {   int blocks = (N + 15) / 16;
        layer1A_node_kernel<<<blocks, 256, 0, stream>>>(
            Ax, rowptr_s, comp1, basis1, msg, N);
    }
    {   long total = (long)N * 8;
        layer1B_kernel<<<(int)((total + 255) / 256), 256, 0, stream>>>(
            e2, rowptr, msg, root1, bias1, h, sinv, N);
    }
    {   long total = (long)N * 4;
        layer2_kernel<<<(int)((total + 255) / 256), 256, 0, stream>>>(
            e2, rowptr, sinv, w2, h, root2, bias2, out, N);
    }
}